// Round 1
// baseline (483.231 us; speedup 1.0000x reference)
//
#include <hip/hip_runtime.h>

#define N_NODES 20000
#define N_EDGES 320000
#define ET (N_EDGES + N_NODES)   // 340000 edges incl self-loops
#define F_IN 1024
#define HC 256                   // H*C for layers 1,2
#define NC 4

// ---------------- CSR build ----------------
__global__ void count_kernel(const int* __restrict__ ei, int* __restrict__ counts) {
    int e = blockIdx.x * blockDim.x + threadIdx.x;
    if (e >= ET) return;
    int dst = (e < N_EDGES) ? ei[N_EDGES + e] : (e - N_EDGES);
    atomicAdd(&counts[dst], 1);
}

__global__ void scan_kernel(const int* __restrict__ counts, int* __restrict__ row_ptr,
                            int* __restrict__ cursor) {
    __shared__ int sums[1024];
    int t = threadIdx.x;
    const int per = (N_NODES + 1023) / 1024;   // 20
    int b = t * per;
    int e = min(b + per, N_NODES);
    int s = 0;
    for (int i = b; i < e; ++i) s += counts[i];
    sums[t] = s;
    __syncthreads();
    for (int off = 1; off < 1024; off <<= 1) {
        int v = (t >= off) ? sums[t - off] : 0;
        __syncthreads();
        sums[t] += v;
        __syncthreads();
    }
    int run = (t == 0) ? 0 : sums[t - 1];
    for (int i = b; i < e; ++i) {
        row_ptr[i] = run;
        cursor[i]  = run;
        run += counts[i];
    }
    if (t == 0) row_ptr[N_NODES] = ET;
}

__global__ void scatter_kernel(const int* __restrict__ ei, int* __restrict__ cursor,
                               int* __restrict__ col) {
    int e = blockIdx.x * blockDim.x + threadIdx.x;
    if (e >= ET) return;
    int src, dst;
    if (e < N_EDGES) { src = ei[e]; dst = ei[N_EDGES + e]; }
    else             { src = dst = e - N_EDGES; }
    int pos = atomicAdd(&cursor[dst], 1);
    col[pos] = src;
}

// ---------------- fp32 tiled GEMM: C[M,N] = A[M,K] @ B[K,N] ----------------
// 64x64 tile, BK=16, 256 threads, 4x4 per thread. N,K multiples of 64/16; M guarded.
__global__ void gemm_kernel(const float* __restrict__ A, const float* __restrict__ B,
                            float* __restrict__ Cm, int M, int N, int K) {
    __shared__ float As[16][64];
    __shared__ float Bs[16][64];
    int t  = threadIdx.x;
    int tx = t % 16, ty = t / 16;
    int bm = blockIdx.x * 64;
    int bn = blockIdx.y * 64;
    float acc[4][4] = {};
    int ar = t / 4;            // A tile row 0..63
    int ak = (t % 4) * 4;      // A tile k 0,4,8,12
    int br = t / 16;           // B tile row 0..15
    int bc = (t % 16) * 4;     // B tile col
    for (int k0 = 0; k0 < K; k0 += 16) {
        float4 av;
        int arow = bm + ar;
        if (arow < M) av = *reinterpret_cast<const float4*>(&A[(size_t)arow * K + k0 + ak]);
        else          av = make_float4(0.f, 0.f, 0.f, 0.f);
        As[ak + 0][ar] = av.x; As[ak + 1][ar] = av.y;
        As[ak + 2][ar] = av.z; As[ak + 3][ar] = av.w;
        float4 bv = *reinterpret_cast<const float4*>(&B[(size_t)(k0 + br) * N + bn + bc]);
        *reinterpret_cast<float4*>(&Bs[br][bc]) = bv;
        __syncthreads();
        #pragma unroll
        for (int kk = 0; kk < 16; ++kk) {
            float a[4], b[4];
            #pragma unroll
            for (int i = 0; i < 4; ++i) a[i] = As[kk][ty * 4 + i];
            #pragma unroll
            for (int j = 0; j < 4; ++j) b[j] = Bs[kk][tx * 4 + j];
            #pragma unroll
            for (int i = 0; i < 4; ++i)
                #pragma unroll
                for (int j = 0; j < 4; ++j)
                    acc[i][j] += a[i] * b[j];
        }
        __syncthreads();
    }
    #pragma unroll
    for (int i = 0; i < 4; ++i) {
        int row = bm + ty * 4 + i;
        if (row >= M) continue;
        #pragma unroll
        for (int j = 0; j < 4; ++j)
            Cm[(size_t)row * N + bn + tx * 4 + j] = acc[i][j];
    }
}

// ---------------- attention logits: als/ald [N,H] from h [N,H*C] ----------------
template<int H>
__global__ void al_kernel(const float* __restrict__ h, const float* __restrict__ as_w,
                          const float* __restrict__ ad_w, float* __restrict__ als,
                          float* __restrict__ ald) {
    int n = blockIdx.x;
    int t = threadIdx.x;             // H*64 threads; each head = one wave
    float hv = h[(size_t)n * (H * 64) + t];
    float s = hv * as_w[t];
    float d = hv * ad_w[t];
    #pragma unroll
    for (int off = 32; off > 0; off >>= 1) {
        s += __shfl_down(s, off, 64);
        d += __shfl_down(d, off, 64);
    }
    if ((t & 63) == 0) {
        int head = t >> 6;
        als[n * H + head] = s;
        ald[n * H + head] = d;
    }
}

// ---------------- per-dst segment softmax + weighted aggregation ----------------
template<int H, int Cc, bool RELU>
__global__ void agg_kernel(const float* __restrict__ h, const float* __restrict__ als,
                           const float* __restrict__ ald, const int* __restrict__ row_ptr,
                           const int* __restrict__ col, const float* __restrict__ bias,
                           float* __restrict__ out) {
    const int HCl = H * Cc;
    int dst = blockIdx.x;
    int t = threadIdx.x;             // HCl threads
    int beg = row_ptr[dst], end = row_ptr[dst + 1];
    int deg = end - beg;
    __shared__ float s_m[H], s_den[H];
    __shared__ int   s_src[64];
    __shared__ float s_alpha[64 * H];

    if (t < 64) {
        float m[H];
        #pragma unroll
        for (int hh = 0; hh < H; ++hh) m[hh] = -1e30f;
        for (int i = t; i < deg; i += 64) {
            int src = col[beg + i];
            #pragma unroll
            for (int hh = 0; hh < H; ++hh) {
                float e = als[src * H + hh] + ald[dst * H + hh];
                e = (e > 0.f) ? e : 0.2f * e;
                m[hh] = fmaxf(m[hh], e);
            }
        }
        #pragma unroll
        for (int hh = 0; hh < H; ++hh) {
            #pragma unroll
            for (int off = 32; off > 0; off >>= 1)
                m[hh] = fmaxf(m[hh], __shfl_down(m[hh], off, 64));
            m[hh] = __shfl(m[hh], 0, 64);
        }
        float den[H];
        #pragma unroll
        for (int hh = 0; hh < H; ++hh) den[hh] = 0.f;
        for (int i = t; i < deg; i += 64) {
            int src = col[beg + i];
            #pragma unroll
            for (int hh = 0; hh < H; ++hh) {
                float e = als[src * H + hh] + ald[dst * H + hh];
                e = (e > 0.f) ? e : 0.2f * e;
                den[hh] += __expf(e - m[hh]);
            }
        }
        #pragma unroll
        for (int hh = 0; hh < H; ++hh) {
            #pragma unroll
            for (int off = 32; off > 0; off >>= 1)
                den[hh] += __shfl_down(den[hh], off, 64);
        }
        if (t == 0) {
            #pragma unroll
            for (int hh = 0; hh < H; ++hh) {
                s_m[hh]   = m[hh];
                s_den[hh] = 1.f / (den[hh] + 1e-16f);
            }
        }
    }
    __syncthreads();

    float acc = 0.f;
    int head = t / Cc;
    for (int off = 0; off < deg; off += 64) {
        int cn = min(64, deg - off);
        if (t < cn) {
            int src = col[beg + off + t];
            s_src[t] = src;
            #pragma unroll
            for (int hh = 0; hh < H; ++hh) {
                float e = als[src * H + hh] + ald[dst * H + hh];
                e = (e > 0.f) ? e : 0.2f * e;
                s_alpha[t * H + hh] = __expf(e - s_m[hh]) * s_den[hh];
            }
        }
        __syncthreads();
        for (int i = 0; i < cn; ++i)
            acc += s_alpha[i * H + head] * h[(size_t)s_src[i] * HCl + t];
        __syncthreads();
    }
    float v = acc + bias[t];
    if (RELU) v = fmaxf(v, 0.f);
    out[(size_t)dst * HCl + t] = v;
}

// ---------------- classifier: out[N,4] = x[N,64] @ wc[64,4] + bc ----------------
__global__ void classifier_kernel(const float* __restrict__ x, const float* __restrict__ wc,
                                  const float* __restrict__ bc, float* __restrict__ out) {
    int n = blockIdx.x * blockDim.x + threadIdx.x;
    if (n >= N_NODES) return;
    float acc[NC] = {bc[0], bc[1], bc[2], bc[3]};
    for (int c = 0; c < 64; ++c) {
        float xv = x[(size_t)n * 64 + c];
        #pragma unroll
        for (int k = 0; k < NC; ++k) acc[k] += xv * wc[c * NC + k];
    }
    #pragma unroll
    for (int k = 0; k < NC; ++k) out[(size_t)n * NC + k] = acc[k];
}

extern "C" void kernel_launch(void* const* d_in, const int* in_sizes, int n_in,
                              void* d_out, int out_size, void* d_ws, size_t ws_size,
                              hipStream_t stream) {
    const float* x   = (const float*)d_in[0];
    const int*   ei  = (const int*)d_in[1];
    const float* w1  = (const float*)d_in[2];
    const float* as1 = (const float*)d_in[3];
    const float* ad1 = (const float*)d_in[4];
    const float* b1  = (const float*)d_in[5];
    const float* w2  = (const float*)d_in[6];
    const float* as2 = (const float*)d_in[7];
    const float* ad2 = (const float*)d_in[8];
    const float* b2  = (const float*)d_in[9];
    const float* w3  = (const float*)d_in[10];
    const float* as3 = (const float*)d_in[11];
    const float* ad3 = (const float*)d_in[12];
    const float* b3  = (const float*)d_in[13];
    const float* wc  = (const float*)d_in[14];
    const float* bc  = (const float*)d_in[15];
    float* out = (float*)d_out;

    // workspace layout
    float* B0  = (float*)d_ws;                         // [N, 256] h buffer
    float* B1  = B0 + (size_t)N_NODES * HC;            // [N, 256] feature/agg buffer
    float* als = B1 + (size_t)N_NODES * HC;            // [N, 4]
    float* ald = als + (size_t)N_NODES * 4;            // [N, 4]
    int* counts  = (int*)(ald + (size_t)N_NODES * 4);  // [N]
    int* cursor  = counts + N_NODES;                   // [N]
    int* row_ptr = cursor + N_NODES;                   // [N+1]
    int* colidx  = row_ptr + (N_NODES + 1);            // [ET]

    // ---- CSR build (shared by all layers) ----
    hipMemsetAsync(counts, 0, N_NODES * sizeof(int), stream);
    int eb = (ET + 255) / 256;
    count_kernel<<<eb, 256, 0, stream>>>(ei, counts);
    scan_kernel<<<1, 1024, 0, stream>>>(counts, row_ptr, cursor);
    scatter_kernel<<<eb, 256, 0, stream>>>(ei, cursor, colidx);

    dim3 g1((N_NODES + 63) / 64, HC / 64);
    // ---- layer 1 ----
    gemm_kernel<<<g1, 256, 0, stream>>>(x, w1, B0, N_NODES, HC, F_IN);
    al_kernel<4><<<N_NODES, 256, 0, stream>>>(B0, as1, ad1, als, ald);
    agg_kernel<4, 64, true><<<N_NODES, 256, 0, stream>>>(B0, als, ald, row_ptr, colidx, b1, B1);
    // ---- layer 2 ----
    gemm_kernel<<<g1, 256, 0, stream>>>(B1, w2, B0, N_NODES, HC, HC);
    al_kernel<4><<<N_NODES, 256, 0, stream>>>(B0, as2, ad2, als, ald);
    agg_kernel<4, 64, true><<<N_NODES, 256, 0, stream>>>(B0, als, ald, row_ptr, colidx, b2, B1);
    // ---- layer 3 (H=1, C=64, no relu) ----
    dim3 g3((N_NODES + 63) / 64, 1);
    gemm_kernel<<<g3, 256, 0, stream>>>(B1, w3, B0, N_NODES, 64, HC);
    al_kernel<1><<<N_NODES, 64, 0, stream>>>(B0, as3, ad3, als, ald);
    agg_kernel<1, 64, false><<<N_NODES, 64, 0, stream>>>(B0, als, ald, row_ptr, colidx, b3, B1);
    // ---- classifier ----
    classifier_kernel<<<(N_NODES + 255) / 256, 256, 0, stream>>>(B1, wc, bc, out);
}

// Round 2
// 404.440 us; speedup vs baseline: 1.1948x; 1.1948x over previous
//
#include <hip/hip_runtime.h>

#define N_NODES 20000
#define N_EDGES 320000
#define ET (N_EDGES + N_NODES)   // 340000 edges incl self-loops
#define F_IN 1024
#define HC 256                   // H*C for layers 1,2
#define NC 4

typedef unsigned short ushort_t;
typedef __attribute__((ext_vector_type(8))) short short8;
typedef __attribute__((ext_vector_type(4))) float f32x4;

// bf16 <-> f32 via bit ops (RTNE), header-layout independent
__device__ inline ushort_t f2bf(float f) {
    unsigned u = __float_as_uint(f);
    unsigned r = (u + 0x7fffu + ((u >> 16) & 1u)) >> 16;
    return (ushort_t)r;
}
__device__ inline float bf2f(ushort_t u) {
    return __uint_as_float(((unsigned)u) << 16);
}

#define GLOAD16(gp, lp) __builtin_amdgcn_global_load_lds( \
    (const __attribute__((address_space(1))) void*)(gp),  \
    (__attribute__((address_space(3))) void*)(lp), 16, 0, 0)

// ---------------- CSR build ----------------
__global__ void count_kernel(const int* __restrict__ ei, int* __restrict__ counts) {
    int e = blockIdx.x * blockDim.x + threadIdx.x;
    if (e >= ET) return;
    int dst = (e < N_EDGES) ? ei[N_EDGES + e] : (e - N_EDGES);
    atomicAdd(&counts[dst], 1);
}

__global__ void scan_kernel(const int* __restrict__ counts, int* __restrict__ row_ptr,
                            int* __restrict__ cursor) {
    __shared__ int sums[1024];
    int t = threadIdx.x;
    const int per = (N_NODES + 1023) / 1024;
    int b = t * per;
    int e = min(b + per, N_NODES);
    int s = 0;
    for (int i = b; i < e; ++i) s += counts[i];
    sums[t] = s;
    __syncthreads();
    for (int off = 1; off < 1024; off <<= 1) {
        int v = (t >= off) ? sums[t - off] : 0;
        __syncthreads();
        sums[t] += v;
        __syncthreads();
    }
    int run = (t == 0) ? 0 : sums[t - 1];
    for (int i = b; i < e; ++i) {
        row_ptr[i] = run;
        cursor[i]  = run;
        run += counts[i];
    }
    if (t == 0) row_ptr[N_NODES] = ET;
}

__global__ void scatter_kernel(const int* __restrict__ ei, int* __restrict__ cursor,
                               int* __restrict__ col) {
    int e = blockIdx.x * blockDim.x + threadIdx.x;
    if (e >= ET) return;
    int src, dst;
    if (e < N_EDGES) { src = ei[e]; dst = ei[N_EDGES + e]; }
    else             { src = dst = e - N_EDGES; }
    int pos = atomicAdd(&cursor[dst], 1);
    col[pos] = src;
}

// ---------------- split fp32 -> bf16 hi/lo ----------------
__global__ void split_rows(const float* __restrict__ in, ushort_t* __restrict__ hi,
                           ushort_t* __restrict__ lo, int n4) {
    int i = blockIdx.x * blockDim.x + threadIdx.x;
    int stride = gridDim.x * blockDim.x;
    for (; i < n4; i += stride) {
        float4 v = ((const float4*)in)[i];
        ushort4 h, l;
        h.x = f2bf(v.x); l.x = f2bf(v.x - bf2f(h.x));
        h.y = f2bf(v.y); l.y = f2bf(v.y - bf2f(h.y));
        h.z = f2bf(v.z); l.z = f2bf(v.z - bf2f(h.z));
        h.w = f2bf(v.w); l.w = f2bf(v.w - bf2f(h.w));
        ((ushort4*)hi)[i] = h;
        ((ushort4*)lo)[i] = l;
    }
}

// weights: in [K][Nn] fp32 row-major -> out hi/lo as W^T [Nn][K] bf16
__global__ void split_T(const float* __restrict__ in, ushort_t* __restrict__ hi,
                        ushort_t* __restrict__ lo, int K, int Nn) {
    int idx = blockIdx.x * blockDim.x + threadIdx.x;
    if (idx >= K * Nn) return;
    int k = idx / Nn, n = idx - k * Nn;
    float v = in[idx];
    ushort_t h = f2bf(v);
    hi[(size_t)n * K + k] = h;
    lo[(size_t)n * K + k] = f2bf(v - bf2f(h));
}

// ---------------- split-bf16 MFMA GEMM ----------------
// C[M,NT](f32) = (Ah+Al)[M,K] @ (Bh+Bl)[K,*]  (B given transposed: BT [n][k])
// 3 passes: Ah*Bh + Ah*Bl + Al*Bh. BM=128 tile, BN in {128,64}. 256 threads.
template<int BN>
__launch_bounds__(256)
__global__ void gemm_mfma(const ushort_t* __restrict__ Ah, const ushort_t* __restrict__ Al,
                          const ushort_t* __restrict__ BTh, const ushort_t* __restrict__ BTl,
                          float* __restrict__ C, int M, int K, int NT) {
    constexpr int BM = 128;
    constexpr int SN = BN / 2;           // per-wave N extent (2x2 wave grid)
    constexpr int NF = SN / 16;          // n-frags per wave
    constexpr int AQ = BM / 64;          // gload instrs per wave for A tile
    constexpr int BQ = BN / 64;
    __shared__ __align__(16) ushort_t As[BM * 32];
    __shared__ __align__(16) ushort_t Bs[BN * 32];
    const int t = threadIdx.x, lane = t & 63, w = t >> 6;
    const int wm = w >> 1, wn = w & 1;
    const int bm = blockIdx.x * BM, bn = blockIdx.y * BN;

    // per-lane global byte offsets for staging (row-major, K bf16 per row)
    size_t gA[AQ]; int lA[AQ];
    #pragma unroll
    for (int q = 0; q < AQ; ++q) {
        int inst = w * AQ + q;
        int row  = inst * 16 + (lane >> 2);
        int grow = min(bm + row, M - 1);     // clamp tail (dup rows, write-guarded)
        gA[q] = (size_t)grow * K * 2 + (size_t)(lane & 3) * 16;
        lA[q] = inst * 1024;
    }
    size_t gB[BQ]; int lB[BQ];
    #pragma unroll
    for (int q = 0; q < BQ; ++q) {
        int inst = w * BQ + q;
        int row  = inst * 16 + (lane >> 2);
        gB[q] = (size_t)(bn + row) * K * 2 + (size_t)(lane & 3) * 16;
        lB[q] = inst * 1024;
    }

    f32x4 acc[4][NF];
    #pragma unroll
    for (int i = 0; i < 4; ++i)
        #pragma unroll
        for (int j = 0; j < NF; ++j) acc[i][j] = (f32x4){0.f, 0.f, 0.f, 0.f};

    const ushort_t* Ap[3] = {Ah, Ah, Al};
    const ushort_t* Bp[3] = {BTh, BTl, BTh};
    for (int p = 0; p < 3; ++p) {
        const char* Ab = (const char*)Ap[p];
        const char* Bb = (const char*)Bp[p];
        for (int k0 = 0; k0 < K; k0 += 32) {
            size_t kb = (size_t)k0 * 2;
            #pragma unroll
            for (int q = 0; q < AQ; ++q) GLOAD16(Ab + gA[q] + kb, (char*)As + lA[q]);
            #pragma unroll
            for (int q = 0; q < BQ; ++q) GLOAD16(Bb + gB[q] + kb, (char*)Bs + lB[q]);
            __syncthreads();   // compiler drains vmcnt before s_barrier
            short8 af[4], bfr[NF];
            #pragma unroll
            for (int i = 0; i < 4; ++i)
                af[i] = *(const short8*)((const char*)As +
                         (wm * 64 + i * 16 + (lane & 15)) * 64 + (lane >> 4) * 16);
            #pragma unroll
            for (int j = 0; j < NF; ++j)
                bfr[j] = *(const short8*)((const char*)Bs +
                          (wn * SN + j * 16 + (lane & 15)) * 64 + (lane >> 4) * 16);
            #pragma unroll
            for (int i = 0; i < 4; ++i)
                #pragma unroll
                for (int j = 0; j < NF; ++j)
                    acc[i][j] = __builtin_amdgcn_mfma_f32_16x16x32_bf16(af[i], bfr[j], acc[i][j], 0, 0, 0);
            __syncthreads();
        }
    }
    // C/D layout: col = lane&15, row = (lane>>4)*4 + reg   [measured m89/m91]
    #pragma unroll
    for (int i = 0; i < 4; ++i) {
        int rbase = bm + wm * 64 + i * 16 + (lane >> 4) * 4;
        #pragma unroll
        for (int j = 0; j < NF; ++j) {
            int col = bn + wn * SN + j * 16 + (lane & 15);
            #pragma unroll
            for (int r = 0; r < 4; ++r)
                if (rbase + r < M) C[(size_t)(rbase + r) * NT + col] = acc[i][j][r];
        }
    }
}

// ---------------- fp32 tiled GEMM (fallback path) ----------------
__global__ void gemm_kernel(const float* __restrict__ A, const float* __restrict__ B,
                            float* __restrict__ Cm, int M, int N, int K) {
    __shared__ float As[16][64];
    __shared__ float Bs[16][64];
    int t  = threadIdx.x;
    int tx = t % 16, ty = t / 16;
    int bm = blockIdx.x * 64;
    int bn = blockIdx.y * 64;
    float acc[4][4] = {};
    int ar = t / 4;
    int ak = (t % 4) * 4;
    int br = t / 16;
    int bc = (t % 16) * 4;
    for (int k0 = 0; k0 < K; k0 += 16) {
        float4 av;
        int arow = bm + ar;
        if (arow < M) av = *reinterpret_cast<const float4*>(&A[(size_t)arow * K + k0 + ak]);
        else          av = make_float4(0.f, 0.f, 0.f, 0.f);
        As[ak + 0][ar] = av.x; As[ak + 1][ar] = av.y;
        As[ak + 2][ar] = av.z; As[ak + 3][ar] = av.w;
        float4 bv = *reinterpret_cast<const float4*>(&B[(size_t)(k0 + br) * N + bn + bc]);
        *reinterpret_cast<float4*>(&Bs[br][bc]) = bv;
        __syncthreads();
        #pragma unroll
        for (int kk = 0; kk < 16; ++kk) {
            float a[4], b[4];
            #pragma unroll
            for (int i = 0; i < 4; ++i) a[i] = As[kk][ty * 4 + i];
            #pragma unroll
            for (int j = 0; j < 4; ++j) b[j] = Bs[kk][tx * 4 + j];
            #pragma unroll
            for (int i = 0; i < 4; ++i)
                #pragma unroll
                for (int j = 0; j < 4; ++j)
                    acc[i][j] += a[i] * b[j];
        }
        __syncthreads();
    }
    #pragma unroll
    for (int i = 0; i < 4; ++i) {
        int row = bm + ty * 4 + i;
        if (row >= M) continue;
        #pragma unroll
        for (int j = 0; j < 4; ++j)
            Cm[(size_t)row * N + bn + tx * 4 + j] = acc[i][j];
    }
}

// ---------------- attention logits ----------------
template<int H>
__global__ void al_kernel(const float* __restrict__ h, const float* __restrict__ as_w,
                          const float* __restrict__ ad_w, float* __restrict__ als,
                          float* __restrict__ ald) {
    int n = blockIdx.x;
    int t = threadIdx.x;
    float hv = h[(size_t)n * (H * 64) + t];
    float s = hv * as_w[t];
    float d = hv * ad_w[t];
    #pragma unroll
    for (int off = 32; off > 0; off >>= 1) {
        s += __shfl_down(s, off, 64);
        d += __shfl_down(d, off, 64);
    }
    if ((t & 63) == 0) {
        int head = t >> 6;
        als[n * H + head] = s;
        ald[n * H + head] = d;
    }
}

// ---------------- segment softmax + aggregation ----------------
template<int H, int Cc, bool RELU, bool SPLIT>
__global__ void agg_kernel(const float* __restrict__ h, const float* __restrict__ als,
                           const float* __restrict__ ald, const int* __restrict__ row_ptr,
                           const int* __restrict__ col, const float* __restrict__ bias,
                           ushort_t* __restrict__ oh, ushort_t* __restrict__ ol,
                           float* __restrict__ of) {
    const int HCl = H * Cc;
    int dst = blockIdx.x;
    int t = threadIdx.x;
    int beg = row_ptr[dst], end = row_ptr[dst + 1];
    int deg = end - beg;
    __shared__ float s_m[H], s_den[H];
    __shared__ int   s_src[64];
    __shared__ float s_alpha[64 * H];

    if (t < 64) {
        float m[H];
        #pragma unroll
        for (int hh = 0; hh < H; ++hh) m[hh] = -1e30f;
        for (int i = t; i < deg; i += 64) {
            int src = col[beg + i];
            #pragma unroll
            for (int hh = 0; hh < H; ++hh) {
                float e = als[src * H + hh] + ald[dst * H + hh];
                e = (e > 0.f) ? e : 0.2f * e;
                m[hh] = fmaxf(m[hh], e);
            }
        }
        #pragma unroll
        for (int hh = 0; hh < H; ++hh) {
            #pragma unroll
            for (int off = 32; off > 0; off >>= 1)
                m[hh] = fmaxf(m[hh], __shfl_down(m[hh], off, 64));
            m[hh] = __shfl(m[hh], 0, 64);
        }
        float den[H];
        #pragma unroll
        for (int hh = 0; hh < H; ++hh) den[hh] = 0.f;
        for (int i = t; i < deg; i += 64) {
            int src = col[beg + i];
            #pragma unroll
            for (int hh = 0; hh < H; ++hh) {
                float e = als[src * H + hh] + ald[dst * H + hh];
                e = (e > 0.f) ? e : 0.2f * e;
                den[hh] += __expf(e - m[hh]);
            }
        }
        #pragma unroll
        for (int hh = 0; hh < H; ++hh) {
            #pragma unroll
            for (int off = 32; off > 0; off >>= 1)
                den[hh] += __shfl_down(den[hh], off, 64);
        }
        if (t == 0) {
            #pragma unroll
            for (int hh = 0; hh < H; ++hh) {
                s_m[hh]   = m[hh];
                s_den[hh] = 1.f / (den[hh] + 1e-16f);
            }
        }
    }
    __syncthreads();

    float acc = 0.f;
    int head = t / Cc;
    for (int off = 0; off < deg; off += 64) {
        int cn = min(64, deg - off);
        if (t < cn) {
            int src = col[beg + off + t];
            s_src[t] = src;
            #pragma unroll
            for (int hh = 0; hh < H; ++hh) {
                float e = als[src * H + hh] + ald[dst * H + hh];
                e = (e > 0.f) ? e : 0.2f * e;
                s_alpha[t * H + hh] = __expf(e - s_m[hh]) * s_den[hh];
            }
        }
        __syncthreads();
        for (int i = 0; i < cn; ++i)
            acc += s_alpha[i * H + head] * h[(size_t)s_src[i] * HCl + t];
        __syncthreads();
    }
    float v = acc + bias[t];
    if (RELU) v = fmaxf(v, 0.f);
    size_t idx = (size_t)dst * HCl + t;
    if (SPLIT) {
        ushort_t hv16 = f2bf(v);
        oh[idx] = hv16;
        ol[idx] = f2bf(v - bf2f(hv16));
    } else {
        of[idx] = v;
    }
}

// ---------------- classifier ----------------
__global__ void classifier_kernel(const float* __restrict__ x, const float* __restrict__ wc,
                                  const float* __restrict__ bc, float* __restrict__ out) {
    int n = blockIdx.x * blockDim.x + threadIdx.x;
    if (n >= N_NODES) return;
    float acc[NC] = {bc[0], bc[1], bc[2], bc[3]};
    for (int c = 0; c < 64; ++c) {
        float xv = x[(size_t)n * 64 + c];
        #pragma unroll
        for (int k = 0; k < NC; ++k) acc[k] += xv * wc[c * NC + k];
    }
    #pragma unroll
    for (int k = 0; k < NC; ++k) out[(size_t)n * NC + k] = acc[k];
}

extern "C" void kernel_launch(void* const* d_in, const int* in_sizes, int n_in,
                              void* d_out, int out_size, void* d_ws, size_t ws_size,
                              hipStream_t stream) {
    const float* x   = (const float*)d_in[0];
    const int*   ei  = (const int*)d_in[1];
    const float* w1  = (const float*)d_in[2];
    const float* as1 = (const float*)d_in[3];
    const float* ad1 = (const float*)d_in[4];
    const float* b1  = (const float*)d_in[5];
    const float* w2  = (const float*)d_in[6];
    const float* as2 = (const float*)d_in[7];
    const float* ad2 = (const float*)d_in[8];
    const float* b2  = (const float*)d_in[9];
    const float* w3  = (const float*)d_in[10];
    const float* as3 = (const float*)d_in[11];
    const float* ad3 = (const float*)d_in[12];
    const float* b3  = (const float*)d_in[13];
    const float* wc  = (const float*)d_in[14];
    const float* bc  = (const float*)d_in[15];
    float* out = (float*)d_out;

    char* ws = (char*)d_ws;
    size_t off = 0;
    auto alloc = [&](size_t bytes) -> char* {
        char* p = ws + off;
        off = (off + bytes + 255) & ~(size_t)255;
        return p;
    };

    // shared allocations (both paths)
    int* counts  = (int*)alloc(N_NODES * 4);
    int* cursor  = (int*)alloc(N_NODES * 4);
    int* row_ptr = (int*)alloc((N_NODES + 1) * 4);
    int* colidx  = (int*)alloc(ET * 4);
    float* als   = (float*)alloc(N_NODES * 4 * 4);
    float* ald   = (float*)alloc(N_NODES * 4 * 4);
    float* B0    = (float*)alloc((size_t)N_NODES * HC * 4);   // gemm outputs (h)

    // new-path allocations
    size_t off_shared = off;
    ushort_t* xh   = (ushort_t*)alloc((size_t)N_NODES * F_IN * 2);
    ushort_t* xl   = (ushort_t*)alloc((size_t)N_NODES * F_IN * 2);
    ushort_t* w1Th = (ushort_t*)alloc((size_t)F_IN * HC * 2);
    ushort_t* w1Tl = (ushort_t*)alloc((size_t)F_IN * HC * 2);
    ushort_t* w2Th = (ushort_t*)alloc((size_t)HC * HC * 2);
    ushort_t* w2Tl = (ushort_t*)alloc((size_t)HC * HC * 2);
    ushort_t* w3Th = (ushort_t*)alloc((size_t)HC * 64 * 2);
    ushort_t* w3Tl = (ushort_t*)alloc((size_t)HC * 64 * 2);
    ushort_t* B1h  = (ushort_t*)alloc((size_t)N_NODES * HC * 2);
    ushort_t* B1l  = (ushort_t*)alloc((size_t)N_NODES * HC * 2);
    float*    B1f  = (float*)alloc((size_t)N_NODES * 64 * 4);
    bool use_mfma = (off <= ws_size);

    // ---- CSR build ----
    hipMemsetAsync(counts, 0, N_NODES * sizeof(int), stream);
    int eb = (ET + 255) / 256;
    count_kernel<<<eb, 256, 0, stream>>>(ei, counts);
    scan_kernel<<<1, 1024, 0, stream>>>(counts, row_ptr, cursor);
    scatter_kernel<<<eb, 256, 0, stream>>>(ei, cursor, colidx);

    if (use_mfma) {
        // ---- precision split of inputs/weights ----
        split_rows<<<2048, 256, 0, stream>>>(x, xh, xl, (int)((size_t)N_NODES * F_IN / 4));
        split_T<<<(F_IN * HC + 255) / 256, 256, 0, stream>>>(w1, w1Th, w1Tl, F_IN, HC);
        split_T<<<(HC * HC + 255) / 256, 256, 0, stream>>>(w2, w2Th, w2Tl, HC, HC);
        split_T<<<(HC * 64 + 255) / 256, 256, 0, stream>>>(w3, w3Th, w3Tl, HC, 64);

        dim3 g1((N_NODES + 127) / 128, HC / 128);
        // ---- layer 1 ----
        gemm_mfma<128><<<g1, 256, 0, stream>>>(xh, xl, w1Th, w1Tl, B0, N_NODES, F_IN, HC);
        al_kernel<4><<<N_NODES, 256, 0, stream>>>(B0, as1, ad1, als, ald);
        agg_kernel<4, 64, true, true><<<N_NODES, 256, 0, stream>>>(B0, als, ald, row_ptr, colidx, b1, B1h, B1l, nullptr);
        // ---- layer 2 ----
        gemm_mfma<128><<<g1, 256, 0, stream>>>(B1h, B1l, w2Th, w2Tl, B0, N_NODES, HC, HC);
        al_kernel<4><<<N_NODES, 256, 0, stream>>>(B0, as2, ad2, als, ald);
        agg_kernel<4, 64, true, true><<<N_NODES, 256, 0, stream>>>(B0, als, ald, row_ptr, colidx, b2, B1h, B1l, nullptr);
        // ---- layer 3 (H=1, C=64) ----
        dim3 g3((N_NODES + 127) / 128, 1);
        gemm_mfma<64><<<g3, 256, 0, stream>>>(B1h, B1l, w3Th, w3Tl, B0, N_NODES, HC, 64);
        al_kernel<1><<<N_NODES, 64, 0, stream>>>(B0, as3, ad3, als, ald);
        agg_kernel<1, 64, false, false><<<N_NODES, 64, 0, stream>>>(B0, als, ald, row_ptr, colidx, b3, nullptr, nullptr, B1f);
        // ---- classifier ----
        classifier_kernel<<<(N_NODES + 255) / 256, 256, 0, stream>>>(B1f, wc, bc, out);
    } else {
        // fallback: fp32 pipeline (round-1 proven)
        off = off_shared;
        float* B1 = (float*)alloc((size_t)N_NODES * HC * 4);
        dim3 g1((N_NODES + 63) / 64, HC / 64);
        gemm_kernel<<<g1, 256, 0, stream>>>(x, w1, B0, N_NODES, HC, F_IN);
        al_kernel<4><<<N_NODES, 256, 0, stream>>>(B0, as1, ad1, als, ald);
        agg_kernel<4, 64, true, false><<<N_NODES, 256, 0, stream>>>(B0, als, ald, row_ptr, colidx, b1, nullptr, nullptr, B1);
        gemm_kernel<<<g1, 256, 0, stream>>>(B1, w2, B0, N_NODES, HC, HC);
        al_kernel<4><<<N_NODES, 256, 0, stream>>>(B0, as2, ad2, als, ald);
        agg_kernel<4, 64, true, false><<<N_NODES, 256, 0, stream>>>(B0, als, ald, row_ptr, colidx, b2, nullptr, nullptr, B1);
        dim3 g3((N_NODES + 63) / 64, 1);
        gemm_kernel<<<g3, 256, 0, stream>>>(B1, w3, B0, N_NODES, 64, HC);
        al_kernel<1><<<N_NODES, 64, 0, stream>>>(B0, as3, ad3, als, ald);
        agg_kernel<1, 64, false, false><<<N_NODES, 64, 0, stream>>>(B0, als, ald, row_ptr, colidx, b3, nullptr, nullptr, B1);
        classifier_kernel<<<(N_NODES + 255) / 256, 256, 0, stream>>>(B1, wc, bc, out);
    }
}

// Round 3
// 391.401 us; speedup vs baseline: 1.2346x; 1.0333x over previous
//
#include <hip/hip_runtime.h>

#define N_NODES 20000
#define N_EDGES 320000
#define ET (N_EDGES + N_NODES)   // 340000 edges incl self-loops
#define F_IN 1024
#define HC 256                   // H*C for layers 1,2
#define NC 4

typedef unsigned short ushort_t;
typedef __attribute__((ext_vector_type(8))) short short8;
typedef __attribute__((ext_vector_type(4))) float f32x4;

// bf16 <-> f32 via bit ops (RTNE)
__device__ inline ushort_t f2bf(float f) {
    unsigned u = __float_as_uint(f);
    unsigned r = (u + 0x7fffu + ((u >> 16) & 1u)) >> 16;
    return (ushort_t)r;
}
__device__ inline float bf2f(ushort_t u) {
    return __uint_as_float(((unsigned)u) << 16);
}

#define GLOAD16(gp, lp) __builtin_amdgcn_global_load_lds( \
    (const __attribute__((address_space(1))) void*)(gp),  \
    (__attribute__((address_space(3))) void*)(lp), 16, 0, 0)

// ---------------- CSR build ----------------
__global__ void count_kernel(const int* __restrict__ ei, int* __restrict__ counts) {
    int e = blockIdx.x * blockDim.x + threadIdx.x;
    if (e >= ET) return;
    int dst = (e < N_EDGES) ? ei[N_EDGES + e] : (e - N_EDGES);
    atomicAdd(&counts[dst], 1);
}

__global__ void scan_kernel(const int* __restrict__ counts, int* __restrict__ row_ptr,
                            int* __restrict__ cursor) {
    __shared__ int sums[1024];
    int t = threadIdx.x;
    const int per = (N_NODES + 1023) / 1024;
    int b = t * per;
    int e = min(b + per, N_NODES);
    int s = 0;
    for (int i = b; i < e; ++i) s += counts[i];
    sums[t] = s;
    __syncthreads();
    for (int off = 1; off < 1024; off <<= 1) {
        int v = (t >= off) ? sums[t - off] : 0;
        __syncthreads();
        sums[t] += v;
        __syncthreads();
    }
    int run = (t == 0) ? 0 : sums[t - 1];
    for (int i = b; i < e; ++i) {
        row_ptr[i] = run;
        cursor[i]  = run;
        run += counts[i];
    }
    if (t == 0) row_ptr[N_NODES] = ET;
}

__global__ void scatter_kernel(const int* __restrict__ ei, int* __restrict__ cursor,
                               int* __restrict__ col) {
    int e = blockIdx.x * blockDim.x + threadIdx.x;
    if (e >= ET) return;
    int src, dst;
    if (e < N_EDGES) { src = ei[e]; dst = ei[N_EDGES + e]; }
    else             { src = dst = e - N_EDGES; }
    int pos = atomicAdd(&cursor[dst], 1);
    col[pos] = src;
}

// ---------------- split fp32 -> bf16 hi/lo ----------------
__global__ void split_rows(const float* __restrict__ in, ushort_t* __restrict__ hi,
                           ushort_t* __restrict__ lo, int n4) {
    int i = blockIdx.x * blockDim.x + threadIdx.x;
    int stride = gridDim.x * blockDim.x;
    for (; i < n4; i += stride) {
        float4 v = ((const float4*)in)[i];
        ushort4 h, l;
        h.x = f2bf(v.x); l.x = f2bf(v.x - bf2f(h.x));
        h.y = f2bf(v.y); l.y = f2bf(v.y - bf2f(h.y));
        h.z = f2bf(v.z); l.z = f2bf(v.z - bf2f(h.z));
        h.w = f2bf(v.w); l.w = f2bf(v.w - bf2f(h.w));
        ((ushort4*)hi)[i] = h;
        ((ushort4*)lo)[i] = l;
    }
}

// weights: in [K][Nn] fp32 row-major -> hi/lo W^T [Nn][K] bf16
__global__ void split_T(const float* __restrict__ in, ushort_t* __restrict__ hi,
                        ushort_t* __restrict__ lo, int K, int Nn) {
    int idx = blockIdx.x * blockDim.x + threadIdx.x;
    if (idx >= K * Nn) return;
    int k = idx / Nn, n = idx - k * Nn;
    float v = in[idx];
    ushort_t h = f2bf(v);
    hi[(size_t)n * K + k] = h;
    lo[(size_t)n * K + k] = f2bf(v - bf2f(h));
}

// ---------------- fused split-bf16 MFMA GEMM ----------------
// C[M,NT](f32) = (Ah+Al)[M,K] @ (Bh+Bl)  (B given transposed: BT[n][k])
// One K-loop; per phase: stage Ah,Al,Bh,Bl and do AhBh + AhBl + AlBh into one acc.
// LDS swizzle: 16B-chunk' = chunk ^ ((row>>1)&3), applied to pre-swizzled global
// source (global_load_lds writes linearly) AND to the ds_read address.
template<int BM, int BN>
__launch_bounds__(256)
__global__ void gemm_mfma(const ushort_t* __restrict__ Ah, const ushort_t* __restrict__ Al,
                          const ushort_t* __restrict__ BTh, const ushort_t* __restrict__ BTl,
                          float* __restrict__ C, int M, int K, int NT) {
    constexpr int SM = BM / 2;       // per-wave M extent (2x2 wave grid)
    constexpr int SN = BN / 2;
    constexpr int MF = SM / 16;
    constexpr int NF = SN / 16;
    constexpr int AQ = BM / 64;      // gload instrs per wave per A half-tile
    constexpr int BQ = BN / 64;
    __shared__ __align__(16) ushort_t smem[(2 * BM + 2 * BN) * 32];
    char* Ash = (char*)smem;
    char* Asl = Ash + BM * 64;
    char* Bsh = Asl + BM * 64;
    char* Bsl = Bsh + BN * 64;

    const int t = threadIdx.x, lane = t & 63, w = t >> 6;
    const int wm = w >> 1, wn = w & 1;
    const int bm = blockIdx.x * BM, bn = blockIdx.y * BN;
    const int gchunk = ((lane & 3) ^ ((lane >> 3) & 3)) * 16;  // pre-swizzled source

    size_t gA[AQ]; int lA[AQ];
    #pragma unroll
    for (int q = 0; q < AQ; ++q) {
        int inst = w * AQ + q;
        int row  = inst * 16 + (lane >> 2);
        int grow = min(bm + row, M - 1);     // clamp tail (dup rows, write-guarded)
        gA[q] = (size_t)grow * K * 2 + gchunk;
        lA[q] = inst * 1024;
    }
    size_t gB[BQ]; int lB[BQ];
    #pragma unroll
    for (int q = 0; q < BQ; ++q) {
        int inst = w * BQ + q;
        int row  = inst * 16 + (lane >> 2);
        gB[q] = (size_t)(bn + row) * K * 2 + gchunk;
        lB[q] = inst * 1024;
    }

    f32x4 acc[MF][NF];
    #pragma unroll
    for (int i = 0; i < MF; ++i)
        #pragma unroll
        for (int j = 0; j < NF; ++j) acc[i][j] = (f32x4){0.f, 0.f, 0.f, 0.f};

    const char* Ahb = (const char*)Ah;
    const char* Alb = (const char*)Al;
    const char* Bhb = (const char*)BTh;
    const char* Blb = (const char*)BTl;
    const int c16 = (lane >> 4);     // k-chunk index 0..3

    for (int k0 = 0; k0 < K; k0 += 32) {
        size_t kb = (size_t)k0 * 2;
        #pragma unroll
        for (int q = 0; q < AQ; ++q) {
            GLOAD16(Ahb + gA[q] + kb, Ash + lA[q]);
            GLOAD16(Alb + gA[q] + kb, Asl + lA[q]);
        }
        #pragma unroll
        for (int q = 0; q < BQ; ++q) {
            GLOAD16(Bhb + gB[q] + kb, Bsh + lB[q]);
            GLOAD16(Blb + gB[q] + kb, Bsl + lB[q]);
        }
        __syncthreads();   // compiler drains vmcnt before s_barrier
        short8 afh[MF], afl[MF], bfh[NF], bfl[NF];
        #pragma unroll
        for (int i = 0; i < MF; ++i) {
            int row = wm * SM + i * 16 + (lane & 15);
            int off = row * 64 + ((c16 ^ ((row >> 1) & 3)) * 16);
            afh[i] = *(const short8*)(Ash + off);
            afl[i] = *(const short8*)(Asl + off);
        }
        #pragma unroll
        for (int j = 0; j < NF; ++j) {
            int row = wn * SN + j * 16 + (lane & 15);
            int off = row * 64 + ((c16 ^ ((row >> 1) & 3)) * 16);
            bfh[j] = *(const short8*)(Bsh + off);
            bfl[j] = *(const short8*)(Bsl + off);
        }
        #pragma unroll
        for (int i = 0; i < MF; ++i)
            #pragma unroll
            for (int j = 0; j < NF; ++j) {
                acc[i][j] = __builtin_amdgcn_mfma_f32_16x16x32_bf16(afh[i], bfh[j], acc[i][j], 0, 0, 0);
                acc[i][j] = __builtin_amdgcn_mfma_f32_16x16x32_bf16(afh[i], bfl[j], acc[i][j], 0, 0, 0);
                acc[i][j] = __builtin_amdgcn_mfma_f32_16x16x32_bf16(afl[i], bfh[j], acc[i][j], 0, 0, 0);
            }
        __syncthreads();
    }
    // C/D layout: col = lane&15, row = (lane>>4)*4 + reg
    #pragma unroll
    for (int i = 0; i < MF; ++i) {
        int rbase = bm + wm * SM + i * 16 + (lane >> 4) * 4;
        #pragma unroll
        for (int j = 0; j < NF; ++j) {
            int col = bn + wn * SN + j * 16 + (lane & 15);
            #pragma unroll
            for (int r = 0; r < 4; ++r)
                if (rbase + r < M) C[(size_t)(rbase + r) * NT + col] = acc[i][j][r];
        }
    }
}

// ---------------- fp32 tiled GEMM (fallback path) ----------------
__global__ void gemm_kernel(const float* __restrict__ A, const float* __restrict__ B,
                            float* __restrict__ Cm, int M, int N, int K) {
    __shared__ float As[16][64];
    __shared__ float Bs[16][64];
    int t  = threadIdx.x;
    int tx = t % 16, ty = t / 16;
    int bm = blockIdx.x * 64;
    int bn = blockIdx.y * 64;
    float acc[4][4] = {};
    int ar = t / 4;
    int ak = (t % 4) * 4;
    int br = t / 16;
    int bc = (t % 16) * 4;
    for (int k0 = 0; k0 < K; k0 += 16) {
        float4 av;
        int arow = bm + ar;
        if (arow < M) av = *reinterpret_cast<const float4*>(&A[(size_t)arow * K + k0 + ak]);
        else          av = make_float4(0.f, 0.f, 0.f, 0.f);
        As[ak + 0][ar] = av.x; As[ak + 1][ar] = av.y;
        As[ak + 2][ar] = av.z; As[ak + 3][ar] = av.w;
        float4 bv = *reinterpret_cast<const float4*>(&B[(size_t)(k0 + br) * N + bn + bc]);
        *reinterpret_cast<float4*>(&Bs[br][bc]) = bv;
        __syncthreads();
        #pragma unroll
        for (int kk = 0; kk < 16; ++kk) {
            float a[4], b[4];
            #pragma unroll
            for (int i = 0; i < 4; ++i) a[i] = As[kk][ty * 4 + i];
            #pragma unroll
            for (int j = 0; j < 4; ++j) b[j] = Bs[kk][tx * 4 + j];
            #pragma unroll
            for (int i = 0; i < 4; ++i)
                #pragma unroll
                for (int j = 0; j < 4; ++j)
                    acc[i][j] += a[i] * b[j];
        }
        __syncthreads();
    }
    #pragma unroll
    for (int i = 0; i < 4; ++i) {
        int row = bm + ty * 4 + i;
        if (row >= M) continue;
        #pragma unroll
        for (int j = 0; j < 4; ++j)
            Cm[(size_t)row * N + bn + tx * 4 + j] = acc[i][j];
    }
}

// ---------------- attention logits ----------------
template<int H>
__global__ void al_kernel(const float* __restrict__ h, const float* __restrict__ as_w,
                          const float* __restrict__ ad_w, float* __restrict__ als,
                          float* __restrict__ ald) {
    int n = blockIdx.x;
    int t = threadIdx.x;
    float hv = h[(size_t)n * (H * 64) + t];
    float s = hv * as_w[t];
    float d = hv * ad_w[t];
    #pragma unroll
    for (int off = 32; off > 0; off >>= 1) {
        s += __shfl_down(s, off, 64);
        d += __shfl_down(d, off, 64);
    }
    if ((t & 63) == 0) {
        int head = t >> 6;
        als[n * H + head] = s;
        ald[n * H + head] = d;
    }
}

// ---------------- segment softmax + aggregation ----------------
template<int H, int Cc, bool RELU, bool SPLIT>
__global__ void agg_kernel(const float* __restrict__ h, const float* __restrict__ als,
                           const float* __restrict__ ald, const int* __restrict__ row_ptr,
                           const int* __restrict__ col, const float* __restrict__ bias,
                           ushort_t* __restrict__ oh, ushort_t* __restrict__ ol,
                           float* __restrict__ of) {
    const int HCl = H * Cc;
    int dst = blockIdx.x;
    int t = threadIdx.x;
    int beg = row_ptr[dst], end = row_ptr[dst + 1];
    int deg = end - beg;
    __shared__ float s_m[H], s_den[H];
    __shared__ int   s_src[64];
    __shared__ float s_alpha[64 * H];

    if (t < 64) {
        float m[H];
        #pragma unroll
        for (int hh = 0; hh < H; ++hh) m[hh] = -1e30f;
        for (int i = t; i < deg; i += 64) {
            int src = col[beg + i];
            #pragma unroll
            for (int hh = 0; hh < H; ++hh) {
                float e = als[src * H + hh] + ald[dst * H + hh];
                e = (e > 0.f) ? e : 0.2f * e;
                m[hh] = fmaxf(m[hh], e);
            }
        }
        #pragma unroll
        for (int hh = 0; hh < H; ++hh) {
            #pragma unroll
            for (int off = 32; off > 0; off >>= 1)
                m[hh] = fmaxf(m[hh], __shfl_down(m[hh], off, 64));
            m[hh] = __shfl(m[hh], 0, 64);
        }
        float den[H];
        #pragma unroll
        for (int hh = 0; hh < H; ++hh) den[hh] = 0.f;
        for (int i = t; i < deg; i += 64) {
            int src = col[beg + i];
            #pragma unroll
            for (int hh = 0; hh < H; ++hh) {
                float e = als[src * H + hh] + ald[dst * H + hh];
                e = (e > 0.f) ? e : 0.2f * e;
                den[hh] += __expf(e - m[hh]);
            }
        }
        #pragma unroll
        for (int hh = 0; hh < H; ++hh) {
            #pragma unroll
            for (int off = 32; off > 0; off >>= 1)
                den[hh] += __shfl_down(den[hh], off, 64);
        }
        if (t == 0) {
            #pragma unroll
            for (int hh = 0; hh < H; ++hh) {
                s_m[hh]   = m[hh];
                s_den[hh] = 1.f / (den[hh] + 1e-16f);
            }
        }
    }
    __syncthreads();

    float acc = 0.f;
    int head = t / Cc;
    for (int off = 0; off < deg; off += 64) {
        int cn = min(64, deg - off);
        if (t < cn) {
            int src = col[beg + off + t];
            s_src[t] = src;
            #pragma unroll
            for (int hh = 0; hh < H; ++hh) {
                float e = als[src * H + hh] + ald[dst * H + hh];
                e = (e > 0.f) ? e : 0.2f * e;
                s_alpha[t * H + hh] = __expf(e - s_m[hh]) * s_den[hh];
            }
        }
        __syncthreads();
        for (int i = 0; i < cn; ++i)
            acc += s_alpha[i * H + head] * h[(size_t)s_src[i] * HCl + t];
        __syncthreads();
    }
    float v = acc + bias[t];
    if (RELU) v = fmaxf(v, 0.f);
    size_t idx = (size_t)dst * HCl + t;
    if (SPLIT) {
        ushort_t hv16 = f2bf(v);
        oh[idx] = hv16;
        ol[idx] = f2bf(v - bf2f(hv16));
    } else {
        of[idx] = v;
    }
}

// ---------------- classifier ----------------
__global__ void classifier_kernel(const float* __restrict__ x, const float* __restrict__ wc,
                                  const float* __restrict__ bc, float* __restrict__ out) {
    int n = blockIdx.x * blockDim.x + threadIdx.x;
    if (n >= N_NODES) return;
    float acc[NC] = {bc[0], bc[1], bc[2], bc[3]};
    for (int c = 0; c < 64; ++c) {
        float xv = x[(size_t)n * 64 + c];
        #pragma unroll
        for (int k = 0; k < NC; ++k) acc[k] += xv * wc[c * NC + k];
    }
    #pragma unroll
    for (int k = 0; k < NC; ++k) out[(size_t)n * NC + k] = acc[k];
}

extern "C" void kernel_launch(void* const* d_in, const int* in_sizes, int n_in,
                              void* d_out, int out_size, void* d_ws, size_t ws_size,
                              hipStream_t stream) {
    const float* x   = (const float*)d_in[0];
    const int*   ei  = (const int*)d_in[1];
    const float* w1  = (const float*)d_in[2];
    const float* as1 = (const float*)d_in[3];
    const float* ad1 = (const float*)d_in[4];
    const float* b1  = (const float*)d_in[5];
    const float* w2  = (const float*)d_in[6];
    const float* as2 = (const float*)d_in[7];
    const float* ad2 = (const float*)d_in[8];
    const float* b2  = (const float*)d_in[9];
    const float* w3  = (const float*)d_in[10];
    const float* as3 = (const float*)d_in[11];
    const float* ad3 = (const float*)d_in[12];
    const float* b3  = (const float*)d_in[13];
    const float* wc  = (const float*)d_in[14];
    const float* bc  = (const float*)d_in[15];
    float* out = (float*)d_out;

    char* ws = (char*)d_ws;
    size_t off = 0;
    auto alloc = [&](size_t bytes) -> char* {
        char* p = ws + off;
        off = (off + bytes + 255) & ~(size_t)255;
        return p;
    };

    int* counts  = (int*)alloc(N_NODES * 4);
    int* cursor  = (int*)alloc(N_NODES * 4);
    int* row_ptr = (int*)alloc((N_NODES + 1) * 4);
    int* colidx  = (int*)alloc(ET * 4);
    float* als   = (float*)alloc(N_NODES * 4 * 4);
    float* ald   = (float*)alloc(N_NODES * 4 * 4);
    float* B0    = (float*)alloc((size_t)N_NODES * HC * 4);

    size_t off_shared = off;
    ushort_t* xh   = (ushort_t*)alloc((size_t)N_NODES * F_IN * 2);
    ushort_t* xl   = (ushort_t*)alloc((size_t)N_NODES * F_IN * 2);
    ushort_t* w1Th = (ushort_t*)alloc((size_t)F_IN * HC * 2);
    ushort_t* w1Tl = (ushort_t*)alloc((size_t)F_IN * HC * 2);
    ushort_t* w2Th = (ushort_t*)alloc((size_t)HC * HC * 2);
    ushort_t* w2Tl = (ushort_t*)alloc((size_t)HC * HC * 2);
    ushort_t* w3Th = (ushort_t*)alloc((size_t)HC * 64 * 2);
    ushort_t* w3Tl = (ushort_t*)alloc((size_t)HC * 64 * 2);
    ushort_t* B1h  = (ushort_t*)alloc((size_t)N_NODES * HC * 2);
    ushort_t* B1l  = (ushort_t*)alloc((size_t)N_NODES * HC * 2);
    float*    B1f  = (float*)alloc((size_t)N_NODES * 64 * 4);
    bool use_mfma = (off <= ws_size);

    // ---- CSR build ----
    hipMemsetAsync(counts, 0, N_NODES * sizeof(int), stream);
    int eb = (ET + 255) / 256;
    count_kernel<<<eb, 256, 0, stream>>>(ei, counts);
    scan_kernel<<<1, 1024, 0, stream>>>(counts, row_ptr, cursor);
    scatter_kernel<<<eb, 256, 0, stream>>>(ei, cursor, colidx);

    if (use_mfma) {
        split_rows<<<2048, 256, 0, stream>>>(x, xh, xl, (int)((size_t)N_NODES * F_IN / 4));
        split_T<<<(F_IN * HC + 255) / 256, 256, 0, stream>>>(w1, w1Th, w1Tl, F_IN, HC);
        split_T<<<(HC * HC + 255) / 256, 256, 0, stream>>>(w2, w2Th, w2Tl, HC, HC);
        split_T<<<(HC * 64 + 255) / 256, 256, 0, stream>>>(w3, w3Th, w3Tl, HC, 64);

        dim3 g1((N_NODES + 127) / 128, HC / 64);        // 157 x 4
        // ---- layer 1 ----
        gemm_mfma<128, 64><<<g1, 256, 0, stream>>>(xh, xl, w1Th, w1Tl, B0, N_NODES, F_IN, HC);
        al_kernel<4><<<N_NODES, 256, 0, stream>>>(B0, as1, ad1, als, ald);
        agg_kernel<4, 64, true, true><<<N_NODES, 256, 0, stream>>>(B0, als, ald, row_ptr, colidx, b1, B1h, B1l, nullptr);
        // ---- layer 2 ----
        gemm_mfma<128, 64><<<g1, 256, 0, stream>>>(B1h, B1l, w2Th, w2Tl, B0, N_NODES, HC, HC);
        al_kernel<4><<<N_NODES, 256, 0, stream>>>(B0, as2, ad2, als, ald);
        agg_kernel<4, 64, true, true><<<N_NODES, 256, 0, stream>>>(B0, als, ald, row_ptr, colidx, b2, B1h, B1l, nullptr);
        // ---- layer 3 (H=1, C=64) ----
        dim3 g3((N_NODES + 63) / 64, 1);                // 313 x 1
        gemm_mfma<64, 64><<<g3, 256, 0, stream>>>(B1h, B1l, w3Th, w3Tl, B0, N_NODES, HC, 64);
        al_kernel<1><<<N_NODES, 64, 0, stream>>>(B0, as3, ad3, als, ald);
        agg_kernel<1, 64, false, false><<<N_NODES, 64, 0, stream>>>(B0, als, ald, row_ptr, colidx, b3, nullptr, nullptr, B1f);
        // ---- classifier ----
        classifier_kernel<<<(N_NODES + 255) / 256, 256, 0, stream>>>(B1f, wc, bc, out);
    } else {
        off = off_shared;
        float* B1 = (float*)alloc((size_t)N_NODES * HC * 4);
        dim3 g1((N_NODES + 63) / 64, HC / 64);
        gemm_kernel<<<g1, 256, 0, stream>>>(x, w1, B0, N_NODES, HC, F_IN);
        al_kernel<4><<<N_NODES, 256, 0, stream>>>(B0, as1, ad1, als, ald);
        agg_kernel<4, 64, true, false><<<N_NODES, 256, 0, stream>>>(B0, als, ald, row_ptr, colidx, b1, nullptr, nullptr, B1);
        gemm_kernel<<<g1, 256, 0, stream>>>(B1, w2, B0, N_NODES, HC, HC);
        al_kernel<4><<<N_NODES, 256, 0, stream>>>(B0, as2, ad2, als, ald);
        agg_kernel<4, 64, true, false><<<N_NODES, 256, 0, stream>>>(B0, als, ald, row_ptr, colidx, b2, nullptr, nullptr, B1);
        dim3 g3((N_NODES + 63) / 64, 1);
        gemm_kernel<<<g3, 256, 0, stream>>>(B1, w3, B0, N_NODES, 64, HC);
        al_kernel<1><<<N_NODES, 64, 0, stream>>>(B0, as3, ad3, als, ald);
        agg_kernel<1, 64, false, false><<<N_NODES, 64, 0, stream>>>(B0, als, ald, row_ptr, colidx, b3, nullptr, nullptr, B1);
        classifier_kernel<<<(N_NODES + 255) / 256, 256, 0, stream>>>(B1, wc, bc, out);
    }
}

// Round 4
// 376.578 us; speedup vs baseline: 1.2832x; 1.0394x over previous
//
#include <hip/hip_runtime.h>

#define N_NODES 20000
#define N_EDGES 320000
#define ET (N_EDGES + N_NODES)   // 340000 edges incl self-loops
#define F_IN 1024
#define HC 256                   // H*C for layers 1,2
#define NC 4

typedef unsigned short ushort_t;
typedef __attribute__((ext_vector_type(8))) short short8;
typedef __attribute__((ext_vector_type(4))) float f32x4;

// bf16 <-> f32 via bit ops (RTNE)
__device__ inline ushort_t f2bf(float f) {
    unsigned u = __float_as_uint(f);
    unsigned r = (u + 0x7fffu + ((u >> 16) & 1u)) >> 16;
    return (ushort_t)r;
}
__device__ inline float bf2f(ushort_t u) {
    return __uint_as_float(((unsigned)u) << 16);
}

#define GLOAD16(gp, lp) __builtin_amdgcn_global_load_lds( \
    (const __attribute__((address_space(1))) void*)(gp),  \
    (__attribute__((address_space(3))) void*)(lp), 16, 0, 0)

// ---------------- CSR build ----------------
__global__ void count_kernel(const int* __restrict__ ei, int* __restrict__ counts) {
    int e = blockIdx.x * blockDim.x + threadIdx.x;
    if (e >= ET) return;
    int dst = (e < N_EDGES) ? ei[N_EDGES + e] : (e - N_EDGES);
    atomicAdd(&counts[dst], 1);
}

__global__ void scan_kernel(const int* __restrict__ counts, int* __restrict__ row_ptr,
                            int* __restrict__ cursor) {
    __shared__ int sums[1024];
    int t = threadIdx.x;
    const int per = (N_NODES + 1023) / 1024;
    int b = t * per;
    int e = min(b + per, N_NODES);
    int s = 0;
    for (int i = b; i < e; ++i) s += counts[i];
    sums[t] = s;
    __syncthreads();
    for (int off = 1; off < 1024; off <<= 1) {
        int v = (t >= off) ? sums[t - off] : 0;
        __syncthreads();
        sums[t] += v;
        __syncthreads();
    }
    int run = (t == 0) ? 0 : sums[t - 1];
    for (int i = b; i < e; ++i) {
        row_ptr[i] = run;
        cursor[i]  = run;
        run += counts[i];
    }
    if (t == 0) row_ptr[N_NODES] = ET;
}

__global__ void scatter_kernel(const int* __restrict__ ei, int* __restrict__ cursor,
                               int* __restrict__ col) {
    int e = blockIdx.x * blockDim.x + threadIdx.x;
    if (e >= ET) return;
    int src, dst;
    if (e < N_EDGES) { src = ei[e]; dst = ei[N_EDGES + e]; }
    else             { src = dst = e - N_EDGES; }
    int pos = atomicAdd(&cursor[dst], 1);
    col[pos] = src;
}

// ---------------- split fp32 -> bf16 hi/lo ----------------
__global__ void split_rows(const float* __restrict__ in, ushort_t* __restrict__ hi,
                           ushort_t* __restrict__ lo, int n4) {
    int i = blockIdx.x * blockDim.x + threadIdx.x;
    int stride = gridDim.x * blockDim.x;
    for (; i < n4; i += stride) {
        float4 v = ((const float4*)in)[i];
        ushort4 h, l;
        h.x = f2bf(v.x); l.x = f2bf(v.x - bf2f(h.x));
        h.y = f2bf(v.y); l.y = f2bf(v.y - bf2f(h.y));
        h.z = f2bf(v.z); l.z = f2bf(v.z - bf2f(h.z));
        h.w = f2bf(v.w); l.w = f2bf(v.w - bf2f(h.w));
        ((ushort4*)hi)[i] = h;
        ((ushort4*)lo)[i] = l;
    }
}

// weights: in [K][Nn] fp32 row-major -> hi/lo W^T [Nn][K] bf16
__global__ void split_T(const float* __restrict__ in, ushort_t* __restrict__ hi,
                        ushort_t* __restrict__ lo, int K, int Nn) {
    int idx = blockIdx.x * blockDim.x + threadIdx.x;
    if (idx >= K * Nn) return;
    int k = idx / Nn, n = idx - k * Nn;
    float v = in[idx];
    ushort_t h = f2bf(v);
    hi[(size_t)n * K + k] = h;
    lo[(size_t)n * K + k] = f2bf(v - bf2f(h));
}

// ---------------- fused split-bf16 MFMA GEMM ----------------
template<int BM, int BN>
__launch_bounds__(256)
__global__ void gemm_mfma(const ushort_t* __restrict__ Ah, const ushort_t* __restrict__ Al,
                          const ushort_t* __restrict__ BTh, const ushort_t* __restrict__ BTl,
                          float* __restrict__ C, int M, int K, int NT) {
    constexpr int SM = BM / 2;
    constexpr int SN = BN / 2;
    constexpr int MF = SM / 16;
    constexpr int NF = SN / 16;
    constexpr int AQ = BM / 64;
    constexpr int BQ = BN / 64;
    __shared__ __align__(16) ushort_t smem[(2 * BM + 2 * BN) * 32];
    char* Ash = (char*)smem;
    char* Asl = Ash + BM * 64;
    char* Bsh = Asl + BM * 64;
    char* Bsl = Bsh + BN * 64;

    const int t = threadIdx.x, lane = t & 63, w = t >> 6;
    const int wm = w >> 1, wn = w & 1;
    const int bm = blockIdx.x * BM, bn = blockIdx.y * BN;
    const int gchunk = ((lane & 3) ^ ((lane >> 3) & 3)) * 16;  // pre-swizzled source

    size_t gA[AQ]; int lA[AQ];
    #pragma unroll
    for (int q = 0; q < AQ; ++q) {
        int inst = w * AQ + q;
        int row  = inst * 16 + (lane >> 2);
        int grow = min(bm + row, M - 1);
        gA[q] = (size_t)grow * K * 2 + gchunk;
        lA[q] = inst * 1024;
    }
    size_t gB[BQ]; int lB[BQ];
    #pragma unroll
    for (int q = 0; q < BQ; ++q) {
        int inst = w * BQ + q;
        int row  = inst * 16 + (lane >> 2);
        gB[q] = (size_t)(bn + row) * K * 2 + gchunk;
        lB[q] = inst * 1024;
    }

    f32x4 acc[MF][NF];
    #pragma unroll
    for (int i = 0; i < MF; ++i)
        #pragma unroll
        for (int j = 0; j < NF; ++j) acc[i][j] = (f32x4){0.f, 0.f, 0.f, 0.f};

    const char* Ahb = (const char*)Ah;
    const char* Alb = (const char*)Al;
    const char* Bhb = (const char*)BTh;
    const char* Blb = (const char*)BTl;
    const int c16 = (lane >> 4);

    for (int k0 = 0; k0 < K; k0 += 32) {
        size_t kb = (size_t)k0 * 2;
        #pragma unroll
        for (int q = 0; q < AQ; ++q) {
            GLOAD16(Ahb + gA[q] + kb, Ash + lA[q]);
            GLOAD16(Alb + gA[q] + kb, Asl + lA[q]);
        }
        #pragma unroll
        for (int q = 0; q < BQ; ++q) {
            GLOAD16(Bhb + gB[q] + kb, Bsh + lB[q]);
            GLOAD16(Blb + gB[q] + kb, Bsl + lB[q]);
        }
        __syncthreads();
        short8 afh[MF], afl[MF], bfh[NF], bfl[NF];
        #pragma unroll
        for (int i = 0; i < MF; ++i) {
            int row = wm * SM + i * 16 + (lane & 15);
            int off = row * 64 + ((c16 ^ ((row >> 1) & 3)) * 16);
            afh[i] = *(const short8*)(Ash + off);
            afl[i] = *(const short8*)(Asl + off);
        }
        #pragma unroll
        for (int j = 0; j < NF; ++j) {
            int row = wn * SN + j * 16 + (lane & 15);
            int off = row * 64 + ((c16 ^ ((row >> 1) & 3)) * 16);
            bfh[j] = *(const short8*)(Bsh + off);
            bfl[j] = *(const short8*)(Bsl + off);
        }
        #pragma unroll
        for (int i = 0; i < MF; ++i)
            #pragma unroll
            for (int j = 0; j < NF; ++j) {
                acc[i][j] = __builtin_amdgcn_mfma_f32_16x16x32_bf16(afh[i], bfh[j], acc[i][j], 0, 0, 0);
                acc[i][j] = __builtin_amdgcn_mfma_f32_16x16x32_bf16(afh[i], bfl[j], acc[i][j], 0, 0, 0);
                acc[i][j] = __builtin_amdgcn_mfma_f32_16x16x32_bf16(afl[i], bfh[j], acc[i][j], 0, 0, 0);
            }
        __syncthreads();
    }
    #pragma unroll
    for (int i = 0; i < MF; ++i) {
        int rbase = bm + wm * SM + i * 16 + (lane >> 4) * 4;
        #pragma unroll
        for (int j = 0; j < NF; ++j) {
            int col = bn + wn * SN + j * 16 + (lane & 15);
            #pragma unroll
            for (int r = 0; r < 4; ++r)
                if (rbase + r < M) C[(size_t)(rbase + r) * NT + col] = acc[i][j][r];
        }
    }
}

// ---------------- attention logits ----------------
template<int H>
__global__ void al_kernel(const float* __restrict__ h, const float* __restrict__ as_w,
                          const float* __restrict__ ad_w, float* __restrict__ als,
                          float* __restrict__ ald) {
    int n = blockIdx.x;
    int t = threadIdx.x;
    float hv = h[(size_t)n * (H * 64) + t];
    float s = hv * as_w[t];
    float d = hv * ad_w[t];
    #pragma unroll
    for (int off = 32; off > 0; off >>= 1) {
        s += __shfl_down(s, off, 64);
        d += __shfl_down(d, off, 64);
    }
    if ((t & 63) == 0) {
        int head = t >> 6;
        als[n * H + head] = s;
        ald[n * H + head] = d;
    }
}

// ---------------- H=4 aggregation: one dst per 256-thread block ----------------
// Online softmax with all lanes mapped (edge, head); barrier-free unroll-4 gather.
template<bool SPLIT>
__launch_bounds__(256)
__global__ void agg4_kernel(const float* __restrict__ h, const float* __restrict__ als,
                            const float* __restrict__ ald, const int* __restrict__ row_ptr,
                            const int* __restrict__ col, const float* __restrict__ bias,
                            ushort_t* __restrict__ oh, ushort_t* __restrict__ ol,
                            float* __restrict__ of) {
    int dst = blockIdx.x;
    int t = threadIdx.x, lane = t & 63, w = t >> 6;
    int beg = row_ptr[dst], deg = row_ptr[dst + 1] - beg;
    __shared__ float s_redm[4][4], s_redd[4][4];
    __shared__ float s_m[4], s_rden[4];
    __shared__ int   s_src[64];
    __shared__ float s_alpha[64][4];

    int i_loc = t >> 2, hh = t & 3;               // (edge-slot, head)
    float ad = ald[dst * 4 + hh];

    // pass A: online max+den, threads stride 64 edge-slots
    float m = -1e30f, den = 0.f;
    for (int base = 0; base < deg; base += 64) {
        int i = base + i_loc;
        if (i < deg) {
            int src = col[beg + i];
            float e = als[src * 4 + hh] + ad;
            e = (e > 0.f) ? e : 0.2f * e;
            float nm = fmaxf(m, e);
            den = den * __expf(m - nm) + __expf(e - nm);
            m = nm;
        }
    }
    // reduce across same-head lanes within wave (stride-4 groups)
    #pragma unroll
    for (int off = 4; off < 64; off <<= 1) {
        float mo = __shfl_xor(m, off, 64);
        float dn = __shfl_xor(den, off, 64);
        float nm = fmaxf(m, mo);
        den = den * __expf(m - nm) + dn * __expf(mo - nm);
        m = nm;
    }
    if (lane < 4) { s_redm[w][lane] = m; s_redd[w][lane] = den; }
    __syncthreads();
    if (t < 4) {
        float M = -1e30f, D = 0.f;
        #pragma unroll
        for (int ww = 0; ww < 4; ++ww) {
            float mo = s_redm[ww][t], dn = s_redd[ww][t];
            float nm = fmaxf(M, mo);
            D = D * __expf(M - nm) + dn * __expf(mo - nm);
            M = nm;
        }
        s_m[t] = M;
        s_rden[t] = 1.f / (D + 1e-16f);
    }
    __syncthreads();

    // pass B per chunk: alpha to LDS, then gather
    float acc = 0.f;
    float mh = s_m[hh], rdh = s_rden[hh];
    for (int base = 0; base < deg; base += 64) {
        int cn = min(64, deg - base);
        if (i_loc < cn) {
            int src = col[beg + base + i_loc];
            if (hh == 0) s_src[i_loc] = src;
            float e = als[src * 4 + hh] + ad;
            e = (e > 0.f) ? e : 0.2f * e;
            s_alpha[i_loc][hh] = __expf(e - mh) * rdh;
        }
        __syncthreads();
        int kk = 0;
        for (; kk + 4 <= cn; kk += 4) {
            int   s0 = s_src[kk],     s1 = s_src[kk + 1], s2 = s_src[kk + 2], s3 = s_src[kk + 3];
            float a0 = s_alpha[kk][w],     a1 = s_alpha[kk + 1][w];
            float a2 = s_alpha[kk + 2][w], a3 = s_alpha[kk + 3][w];
            float h0 = h[(size_t)s0 * HC + t];
            float h1 = h[(size_t)s1 * HC + t];
            float h2 = h[(size_t)s2 * HC + t];
            float h3 = h[(size_t)s3 * HC + t];
            acc += a0 * h0 + a1 * h1 + a2 * h2 + a3 * h3;
        }
        for (; kk < cn; ++kk)
            acc += s_alpha[kk][w] * h[(size_t)s_src[kk] * HC + t];
        __syncthreads();
    }
    float v = fmaxf(acc + bias[t], 0.f);   // both H=4 layers are ReLU'd
    size_t idx = (size_t)dst * HC + t;
    if (SPLIT) {
        ushort_t hv16 = f2bf(v);
        oh[idx] = hv16;
        ol[idx] = f2bf(v - bf2f(hv16));
    } else {
        of[idx] = v;
    }
}

// ---------------- H=1 aggregation: one WAVE per dst, 4 dst per block ----------------
__launch_bounds__(256)
__global__ void agg1_kernel(const float* __restrict__ h, const float* __restrict__ als,
                            const float* __restrict__ ald, const int* __restrict__ row_ptr,
                            const int* __restrict__ col, const float* __restrict__ bias,
                            float* __restrict__ of) {
    int lane = threadIdx.x & 63, w = threadIdx.x >> 6;
    int dst = blockIdx.x * 4 + w;
    if (dst >= N_NODES) return;
    int beg = row_ptr[dst], deg = row_ptr[dst + 1] - beg;
    float ad = ald[dst];

    // pass A: online per-lane, then full-wave xor reduce
    float m = -1e30f, den = 0.f;
    for (int base = 0; base < deg; base += 64) {
        int i = base + lane;
        if (i < deg) {
            float e = als[col[beg + i]] + ad;
            e = (e > 0.f) ? e : 0.2f * e;
            float nm = fmaxf(m, e);
            den = den * __expf(m - nm) + __expf(e - nm);
            m = nm;
        }
    }
    #pragma unroll
    for (int off = 1; off < 64; off <<= 1) {
        float mo = __shfl_xor(m, off, 64);
        float dn = __shfl_xor(den, off, 64);
        float nm = fmaxf(m, mo);
        den = den * __expf(m - nm) + dn * __expf(mo - nm);
        m = nm;
    }
    float rden = 1.f / (den + 1e-16f);

    float acc = 0.f;
    for (int base = 0; base < deg; base += 64) {
        int cn = min(64, deg - base);
        int   src_v = 0;
        float alp_v = 0.f;
        if (lane < cn) {
            src_v = col[beg + base + lane];
            float e = als[src_v] + ad;
            e = (e > 0.f) ? e : 0.2f * e;
            alp_v = __expf(e - m) * rden;
        }
        int kk = 0;
        for (; kk + 4 <= cn; kk += 4) {
            int   s0 = __shfl(src_v, kk, 64),     s1 = __shfl(src_v, kk + 1, 64);
            int   s2 = __shfl(src_v, kk + 2, 64), s3 = __shfl(src_v, kk + 3, 64);
            float a0 = __shfl(alp_v, kk, 64),     a1 = __shfl(alp_v, kk + 1, 64);
            float a2 = __shfl(alp_v, kk + 2, 64), a3 = __shfl(alp_v, kk + 3, 64);
            float h0 = h[(size_t)s0 * 64 + lane];
            float h1 = h[(size_t)s1 * 64 + lane];
            float h2 = h[(size_t)s2 * 64 + lane];
            float h3 = h[(size_t)s3 * 64 + lane];
            acc += a0 * h0 + a1 * h1 + a2 * h2 + a3 * h3;
        }
        for (; kk < cn; ++kk) {
            int   s = __shfl(src_v, kk, 64);
            float a = __shfl(alp_v, kk, 64);
            acc += a * h[(size_t)s * 64 + lane];
        }
    }
    of[(size_t)dst * 64 + lane] = acc + bias[lane];
}

// ---------------- classifier ----------------
__global__ void classifier_kernel(const float* __restrict__ x, const float* __restrict__ wc,
                                  const float* __restrict__ bc, float* __restrict__ out) {
    int n = blockIdx.x * blockDim.x + threadIdx.x;
    if (n >= N_NODES) return;
    float acc[NC] = {bc[0], bc[1], bc[2], bc[3]};
    for (int c = 0; c < 64; ++c) {
        float xv = x[(size_t)n * 64 + c];
        #pragma unroll
        for (int k = 0; k < NC; ++k) acc[k] += xv * wc[c * NC + k];
    }
    #pragma unroll
    for (int k = 0; k < NC; ++k) out[(size_t)n * NC + k] = acc[k];
}

extern "C" void kernel_launch(void* const* d_in, const int* in_sizes, int n_in,
                              void* d_out, int out_size, void* d_ws, size_t ws_size,
                              hipStream_t stream) {
    const float* x   = (const float*)d_in[0];
    const int*   ei  = (const int*)d_in[1];
    const float* w1  = (const float*)d_in[2];
    const float* as1 = (const float*)d_in[3];
    const float* ad1 = (const float*)d_in[4];
    const float* b1  = (const float*)d_in[5];
    const float* w2  = (const float*)d_in[6];
    const float* as2 = (const float*)d_in[7];
    const float* ad2 = (const float*)d_in[8];
    const float* b2  = (const float*)d_in[9];
    const float* w3  = (const float*)d_in[10];
    const float* as3 = (const float*)d_in[11];
    const float* ad3 = (const float*)d_in[12];
    const float* b3  = (const float*)d_in[13];
    const float* wc  = (const float*)d_in[14];
    const float* bc  = (const float*)d_in[15];
    float* out = (float*)d_out;

    char* ws = (char*)d_ws;
    size_t off = 0;
    auto alloc = [&](size_t bytes) -> char* {
        char* p = ws + off;
        off = (off + bytes + 255) & ~(size_t)255;
        return p;
    };

    int* counts  = (int*)alloc(N_NODES * 4);
    int* cursor  = (int*)alloc(N_NODES * 4);
    int* row_ptr = (int*)alloc((N_NODES + 1) * 4);
    int* colidx  = (int*)alloc(ET * 4);
    float* als   = (float*)alloc(N_NODES * 4 * 4);
    float* ald   = (float*)alloc(N_NODES * 4 * 4);
    float* B0    = (float*)alloc((size_t)N_NODES * HC * 4);

    ushort_t* xh   = (ushort_t*)alloc((size_t)N_NODES * F_IN * 2);
    ushort_t* xl   = (ushort_t*)alloc((size_t)N_NODES * F_IN * 2);
    ushort_t* w1Th = (ushort_t*)alloc((size_t)F_IN * HC * 2);
    ushort_t* w1Tl = (ushort_t*)alloc((size_t)F_IN * HC * 2);
    ushort_t* w2Th = (ushort_t*)alloc((size_t)HC * HC * 2);
    ushort_t* w2Tl = (ushort_t*)alloc((size_t)HC * HC * 2);
    ushort_t* w3Th = (ushort_t*)alloc((size_t)HC * 64 * 2);
    ushort_t* w3Tl = (ushort_t*)alloc((size_t)HC * 64 * 2);
    ushort_t* B1h  = (ushort_t*)alloc((size_t)N_NODES * HC * 2);
    ushort_t* B1l  = (ushort_t*)alloc((size_t)N_NODES * HC * 2);
    float*    B1f  = (float*)alloc((size_t)N_NODES * 64 * 4);

    // ---- CSR build ----
    hipMemsetAsync(counts, 0, N_NODES * sizeof(int), stream);
    int eb = (ET + 255) / 256;
    count_kernel<<<eb, 256, 0, stream>>>(ei, counts);
    scan_kernel<<<1, 1024, 0, stream>>>(counts, row_ptr, cursor);
    scatter_kernel<<<eb, 256, 0, stream>>>(ei, cursor, colidx);

    // ---- precision split ----
    split_rows<<<2048, 256, 0, stream>>>(x, xh, xl, (int)((size_t)N_NODES * F_IN / 4));
    split_T<<<(F_IN * HC + 255) / 256, 256, 0, stream>>>(w1, w1Th, w1Tl, F_IN, HC);
    split_T<<<(HC * HC + 255) / 256, 256, 0, stream>>>(w2, w2Th, w2Tl, HC, HC);
    split_T<<<(HC * 64 + 255) / 256, 256, 0, stream>>>(w3, w3Th, w3Tl, HC, 64);

    dim3 g1((N_NODES + 127) / 128, HC / 64);        // 157 x 4
    // ---- layer 1 ----
    gemm_mfma<128, 64><<<g1, 256, 0, stream>>>(xh, xl, w1Th, w1Tl, B0, N_NODES, F_IN, HC);
    al_kernel<4><<<N_NODES, 256, 0, stream>>>(B0, as1, ad1, als, ald);
    agg4_kernel<true><<<N_NODES, 256, 0, stream>>>(B0, als, ald, row_ptr, colidx, b1, B1h, B1l, nullptr);
    // ---- layer 2 ----
    gemm_mfma<128, 64><<<g1, 256, 0, stream>>>(B1h, B1l, w2Th, w2Tl, B0, N_NODES, HC, HC);
    al_kernel<4><<<N_NODES, 256, 0, stream>>>(B0, as2, ad2, als, ald);
    agg4_kernel<true><<<N_NODES, 256, 0, stream>>>(B0, als, ald, row_ptr, colidx, b2, B1h, B1l, nullptr);
    // ---- layer 3 (H=1, C=64) ----
    dim3 g3((N_NODES + 63) / 64, 1);                // 313 x 1
    gemm_mfma<64, 64><<<g3, 256, 0, stream>>>(B1h, B1l, w3Th, w3Tl, B0, N_NODES, HC, 64);
    al_kernel<1><<<N_NODES, 64, 0, stream>>>(B0, as3, ad3, als, ald);
    agg1_kernel<<<(N_NODES + 3) / 4, 256, 0, stream>>>(B0, als, ald, row_ptr, colidx, b3, B1f);
    // ---- classifier ----
    classifier_kernel<<<(N_NODES + 255) / 256, 256, 0, stream>>>(B1f, wc, bc, out);
}

// Round 5
// 336.421 us; speedup vs baseline: 1.4364x; 1.1194x over previous
//
#include <hip/hip_runtime.h>

#define N_NODES 20000
#define N_EDGES 320000
#define ET (N_EDGES + N_NODES)   // 340000 edges incl self-loops
#define F_IN 1024
#define HC 256                   // H*C for layers 1,2
#define NC 4

typedef unsigned short ushort_t;
typedef __attribute__((ext_vector_type(8))) short short8;
typedef __attribute__((ext_vector_type(4))) float f32x4;

// bf16 <-> f32 via bit ops (RTNE)
__device__ inline ushort_t f2bf(float f) {
    unsigned u = __float_as_uint(f);
    unsigned r = (u + 0x7fffu + ((u >> 16) & 1u)) >> 16;
    return (ushort_t)r;
}
__device__ inline float bf2f(ushort_t u) {
    return __uint_as_float(((unsigned)u) << 16);
}

#define GLOAD16(gp, lp) __builtin_amdgcn_global_load_lds( \
    (const __attribute__((address_space(1))) void*)(gp),  \
    (__attribute__((address_space(3))) void*)(lp), 16, 0, 0)

// ---------------- CSR build ----------------
__global__ void count_kernel(const int* __restrict__ ei, int* __restrict__ counts) {
    int e = blockIdx.x * blockDim.x + threadIdx.x;
    if (e >= ET) return;
    int dst = (e < N_EDGES) ? ei[N_EDGES + e] : (e - N_EDGES);
    atomicAdd(&counts[dst], 1);
}

__global__ void scan_kernel(const int* __restrict__ counts, int* __restrict__ row_ptr,
                            int* __restrict__ cursor) {
    __shared__ int sums[1024];
    int t = threadIdx.x;
    const int per = (N_NODES + 1023) / 1024;
    int b = t * per;
    int e = min(b + per, N_NODES);
    int s = 0;
    for (int i = b; i < e; ++i) s += counts[i];
    sums[t] = s;
    __syncthreads();
    for (int off = 1; off < 1024; off <<= 1) {
        int v = (t >= off) ? sums[t - off] : 0;
        __syncthreads();
        sums[t] += v;
        __syncthreads();
    }
    int run = (t == 0) ? 0 : sums[t - 1];
    for (int i = b; i < e; ++i) {
        row_ptr[i] = run;
        cursor[i]  = run;
        run += counts[i];
    }
    if (t == 0) row_ptr[N_NODES] = ET;
}

__global__ void scatter_kernel(const int* __restrict__ ei, int* __restrict__ cursor,
                               int* __restrict__ col) {
    int e = blockIdx.x * blockDim.x + threadIdx.x;
    if (e >= ET) return;
    int src, dst;
    if (e < N_EDGES) { src = ei[e]; dst = ei[N_EDGES + e]; }
    else             { src = dst = e - N_EDGES; }
    int pos = atomicAdd(&cursor[dst], 1);
    col[pos] = src;
}

// ---------------- split fp32 -> bf16 hi/lo ----------------
__global__ void split_rows(const float* __restrict__ in, ushort_t* __restrict__ hi,
                           ushort_t* __restrict__ lo, int n4) {
    int i = blockIdx.x * blockDim.x + threadIdx.x;
    int stride = gridDim.x * blockDim.x;
    for (; i < n4; i += stride) {
        float4 v = ((const float4*)in)[i];
        ushort4 h, l;
        h.x = f2bf(v.x); l.x = f2bf(v.x - bf2f(h.x));
        h.y = f2bf(v.y); l.y = f2bf(v.y - bf2f(h.y));
        h.z = f2bf(v.z); l.z = f2bf(v.z - bf2f(h.z));
        h.w = f2bf(v.w); l.w = f2bf(v.w - bf2f(h.w));
        ((ushort4*)hi)[i] = h;
        ((ushort4*)lo)[i] = l;
    }
}

// weights: in [K][Nn] fp32 row-major -> hi/lo W^T [Nn][K] bf16
__global__ void split_T(const float* __restrict__ in, ushort_t* __restrict__ hi,
                        ushort_t* __restrict__ lo, int K, int Nn) {
    int idx = blockIdx.x * blockDim.x + threadIdx.x;
    if (idx >= K * Nn) return;
    int k = idx / Nn, n = idx - k * Nn;
    float v = in[idx];
    ushort_t h = f2bf(v);
    hi[(size_t)n * K + k] = h;
    lo[(size_t)n * K + k] = f2bf(v - bf2f(h));
}

// ---------------- fused split-bf16 MFMA GEMM, XCD-swizzled 1D grid ----------------
// logical id chunked per-XCD (m204 bijective); bn fastest so GY blocks sharing an
// A-slice run on the same XCD L2.
template<int BM, int BN, int GY>
__launch_bounds__(256)
__global__ void gemm_mfma(const ushort_t* __restrict__ Ah, const ushort_t* __restrict__ Al,
                          const ushort_t* __restrict__ BTh, const ushort_t* __restrict__ BTl,
                          float* __restrict__ C, int M, int K, int NT) {
    constexpr int SM = BM / 2;
    constexpr int SN = BN / 2;
    constexpr int MF = SM / 16;
    constexpr int NF = SN / 16;
    constexpr int AQ = BM / 64;
    constexpr int BQ = BN / 64;
    __shared__ __align__(16) ushort_t smem[(2 * BM + 2 * BN) * 32];
    char* Ash = (char*)smem;
    char* Asl = Ash + BM * 64;
    char* Bsh = Asl + BM * 64;
    char* Bsl = Bsh + BN * 64;

    const int t = threadIdx.x, lane = t & 63, w = t >> 6;
    const int wm = w >> 1, wn = w & 1;
    // --- bijective XCD chunk swizzle ---
    const int nwg = gridDim.x;
    const int id = blockIdx.x;
    const int q = nwg >> 3, r = nwg & 7;
    const int xcd = id & 7, idx = id >> 3;
    const int logical = (xcd < r ? xcd * (q + 1) : r * (q + 1) + (xcd - r) * q) + idx;
    const int bm = (logical / GY) * BM, bn = (logical % GY) * BN;
    const int gchunk = ((lane & 3) ^ ((lane >> 3) & 3)) * 16;  // pre-swizzled source

    size_t gA[AQ]; int lA[AQ];
    #pragma unroll
    for (int qq = 0; qq < AQ; ++qq) {
        int inst = w * AQ + qq;
        int row  = inst * 16 + (lane >> 2);
        int grow = min(bm + row, M - 1);
        gA[qq] = (size_t)grow * K * 2 + gchunk;
        lA[qq] = inst * 1024;
    }
    size_t gB[BQ]; int lB[BQ];
    #pragma unroll
    for (int qq = 0; qq < BQ; ++qq) {
        int inst = w * BQ + qq;
        int row  = inst * 16 + (lane >> 2);
        gB[qq] = (size_t)(bn + row) * K * 2 + gchunk;
        lB[qq] = inst * 1024;
    }

    f32x4 acc[MF][NF];
    #pragma unroll
    for (int i = 0; i < MF; ++i)
        #pragma unroll
        for (int j = 0; j < NF; ++j) acc[i][j] = (f32x4){0.f, 0.f, 0.f, 0.f};

    const char* Ahb = (const char*)Ah;
    const char* Alb = (const char*)Al;
    const char* Bhb = (const char*)BTh;
    const char* Blb = (const char*)BTl;
    const int c16 = (lane >> 4);

    for (int k0 = 0; k0 < K; k0 += 32) {
        size_t kb = (size_t)k0 * 2;
        #pragma unroll
        for (int qq = 0; qq < AQ; ++qq) {
            GLOAD16(Ahb + gA[qq] + kb, Ash + lA[qq]);
            GLOAD16(Alb + gA[qq] + kb, Asl + lA[qq]);
        }
        #pragma unroll
        for (int qq = 0; qq < BQ; ++qq) {
            GLOAD16(Bhb + gB[qq] + kb, Bsh + lB[qq]);
            GLOAD16(Blb + gB[qq] + kb, Bsl + lB[qq]);
        }
        __syncthreads();
        short8 afh[MF], afl[MF], bfh[NF], bfl[NF];
        #pragma unroll
        for (int i = 0; i < MF; ++i) {
            int row = wm * SM + i * 16 + (lane & 15);
            int off = row * 64 + ((c16 ^ ((row >> 1) & 3)) * 16);
            afh[i] = *(const short8*)(Ash + off);
            afl[i] = *(const short8*)(Asl + off);
        }
        #pragma unroll
        for (int j = 0; j < NF; ++j) {
            int row = wn * SN + j * 16 + (lane & 15);
            int off = row * 64 + ((c16 ^ ((row >> 1) & 3)) * 16);
            bfh[j] = *(const short8*)(Bsh + off);
            bfl[j] = *(const short8*)(Bsl + off);
        }
        #pragma unroll
        for (int i = 0; i < MF; ++i)
            #pragma unroll
            for (int j = 0; j < NF; ++j) {
                acc[i][j] = __builtin_amdgcn_mfma_f32_16x16x32_bf16(afh[i], bfh[j], acc[i][j], 0, 0, 0);
                acc[i][j] = __builtin_amdgcn_mfma_f32_16x16x32_bf16(afh[i], bfl[j], acc[i][j], 0, 0, 0);
                acc[i][j] = __builtin_amdgcn_mfma_f32_16x16x32_bf16(afl[i], bfh[j], acc[i][j], 0, 0, 0);
            }
        __syncthreads();
    }
    #pragma unroll
    for (int i = 0; i < MF; ++i) {
        int rbase = bm + wm * SM + i * 16 + (lane >> 4) * 4;
        #pragma unroll
        for (int j = 0; j < NF; ++j) {
            int col = bn + wn * SN + j * 16 + (lane & 15);
            #pragma unroll
            for (int rr = 0; rr < 4; ++rr)
                if (rbase + rr < M) C[(size_t)(rbase + rr) * NT + col] = acc[i][j][rr];
        }
    }
}

// ---------------- attention logits ----------------
template<int H>
__global__ void al_kernel(const float* __restrict__ h, const float* __restrict__ as_w,
                          const float* __restrict__ ad_w, float* __restrict__ als,
                          float* __restrict__ ald) {
    int n = blockIdx.x;
    int t = threadIdx.x;
    float hv = h[(size_t)n * (H * 64) + t];
    float s = hv * as_w[t];
    float d = hv * ad_w[t];
    #pragma unroll
    for (int off = 32; off > 0; off >>= 1) {
        s += __shfl_down(s, off, 64);
        d += __shfl_down(d, off, 64);
    }
    if ((t & 63) == 0) {
        int head = t >> 6;
        als[n * H + head] = s;
        ald[n * H + head] = d;
    }
}

// ---------------- H=4 aggregation: float4 gather, 4 wave-teams ----------------
template<bool SPLIT>
__launch_bounds__(256)
__global__ void agg4_kernel(const float* __restrict__ h, const float* __restrict__ als,
                            const float* __restrict__ ald, const int* __restrict__ row_ptr,
                            const int* __restrict__ col, const float* __restrict__ bias,
                            ushort_t* __restrict__ oh, ushort_t* __restrict__ ol,
                            float* __restrict__ of) {
    int dst = blockIdx.x;
    int t = threadIdx.x, lane = t & 63, w = t >> 6;
    int beg = row_ptr[dst], deg = row_ptr[dst + 1] - beg;
    __shared__ float s_redm[4][4], s_redd[4][4];
    __shared__ float s_m[4], s_rden[4];
    __shared__ int   s_src[64];
    __shared__ float s_alpha[64][4];
    __shared__ float4 s_part[3][64];

    int i_loc = t >> 2, hh = t & 3;               // (edge-slot, head)
    float ad = ald[dst * 4 + hh];

    // pass A: online max+den over (edge,head)
    float m = -1e30f, den = 0.f;
    for (int base = 0; base < deg; base += 64) {
        int i = base + i_loc;
        if (i < deg) {
            int src = col[beg + i];
            float e = als[src * 4 + hh] + ad;
            e = (e > 0.f) ? e : 0.2f * e;
            float nm = fmaxf(m, e);
            den = den * __expf(m - nm) + __expf(e - nm);
            m = nm;
        }
    }
    #pragma unroll
    for (int off = 4; off < 64; off <<= 1) {
        float mo = __shfl_xor(m, off, 64);
        float dn = __shfl_xor(den, off, 64);
        float nm = fmaxf(m, mo);
        den = den * __expf(m - nm) + dn * __expf(mo - nm);
        m = nm;
    }
    if (lane < 4) { s_redm[w][lane] = m; s_redd[w][lane] = den; }
    __syncthreads();
    if (t < 4) {
        float M = -1e30f, D = 0.f;
        #pragma unroll
        for (int ww = 0; ww < 4; ++ww) {
            float mo = s_redm[ww][t], dn = s_redd[ww][t];
            float nm = fmaxf(M, mo);
            D = D * __expf(M - nm) + dn * __expf(mo - nm);
            M = nm;
        }
        s_m[t] = M;
        s_rden[t] = 1.f / (D + 1e-16f);
    }
    __syncthreads();

    // pass B: alpha to LDS, then team-strided float4 gather
    float mh = s_m[hh], rdh = s_rden[hh];
    float4 acc = make_float4(0.f, 0.f, 0.f, 0.f);
    int c = lane;                 // channel quad 0..63 -> channels 4c..4c+3
    int ghead = c >> 4;
    for (int base = 0; base < deg; base += 64) {
        int cn = min(64, deg - base);
        if (i_loc < cn) {
            int src = col[beg + base + i_loc];
            if (hh == 0) s_src[i_loc] = src;
            float e = als[src * 4 + hh] + ad;
            e = (e > 0.f) ? e : 0.2f * e;
            s_alpha[i_loc][hh] = __expf(e - mh) * rdh;
        }
        __syncthreads();
        for (int e = w; e < cn; e += 4) {
            int src = s_src[e];
            float a = s_alpha[e][ghead];
            float4 hv = *(const float4*)&h[(size_t)src * HC + c * 4];
            acc.x += a * hv.x; acc.y += a * hv.y;
            acc.z += a * hv.z; acc.w += a * hv.w;
        }
        __syncthreads();
    }
    if (w > 0) s_part[w - 1][c] = acc;
    __syncthreads();
    if (w == 0) {
        float4 p1 = s_part[0][c], p2 = s_part[1][c], p3 = s_part[2][c];
        float4 bv = *(const float4*)&bias[c * 4];
        float v0 = fmaxf(((acc.x + p1.x) + p2.x) + p3.x + bv.x, 0.f);
        float v1 = fmaxf(((acc.y + p1.y) + p2.y) + p3.y + bv.y, 0.f);
        float v2 = fmaxf(((acc.z + p1.z) + p2.z) + p3.z + bv.z, 0.f);
        float v3 = fmaxf(((acc.w + p1.w) + p2.w) + p3.w + bv.w, 0.f);
        size_t idx = (size_t)dst * HC + c * 4;
        if (SPLIT) {
            ushort4 h4, l4;
            h4.x = f2bf(v0); l4.x = f2bf(v0 - bf2f(h4.x));
            h4.y = f2bf(v1); l4.y = f2bf(v1 - bf2f(h4.y));
            h4.z = f2bf(v2); l4.z = f2bf(v2 - bf2f(h4.z));
            h4.w = f2bf(v3); l4.w = f2bf(v3 - bf2f(h4.w));
            *(ushort4*)&oh[idx] = h4;
            *(ushort4*)&ol[idx] = l4;
        } else {
            *(float4*)&of[idx] = make_float4(v0, v1, v2, v3);
        }
    }
}

// ---------------- H=1 aggregation: one wave per dst, float4 16-lane teams ----------------
__launch_bounds__(256)
__global__ void agg1_kernel(const float* __restrict__ h, const float* __restrict__ als,
                            const float* __restrict__ ald, const int* __restrict__ row_ptr,
                            const int* __restrict__ col, const float* __restrict__ bias,
                            float* __restrict__ of) {
    __shared__ int   s1_src[4][64];
    __shared__ float s1_alpha[4][64];
    int lane = threadIdx.x & 63, w = threadIdx.x >> 6;
    int dst = blockIdx.x * 4 + w;
    if (dst >= N_NODES) return;
    int beg = row_ptr[dst], deg = row_ptr[dst + 1] - beg;
    float ad = ald[dst];

    float m = -1e30f, den = 0.f;
    for (int base = 0; base < deg; base += 64) {
        int i = base + lane;
        if (i < deg) {
            float e = als[col[beg + i]] + ad;
            e = (e > 0.f) ? e : 0.2f * e;
            float nm = fmaxf(m, e);
            den = den * __expf(m - nm) + __expf(e - nm);
            m = nm;
        }
    }
    #pragma unroll
    for (int off = 1; off < 64; off <<= 1) {
        float mo = __shfl_xor(m, off, 64);
        float dn = __shfl_xor(den, off, 64);
        float nm = fmaxf(m, mo);
        den = den * __expf(m - nm) + dn * __expf(mo - nm);
        m = nm;
    }
    float rden = 1.f / (den + 1e-16f);

    float4 acc = make_float4(0.f, 0.f, 0.f, 0.f);
    int c = lane & 15, team = lane >> 4;
    for (int base = 0; base < deg; base += 64) {
        int cn = min(64, deg - base);
        if (lane < cn) {
            int src = col[beg + base + lane];
            s1_src[w][lane] = src;
            float e = als[src] + ad;
            e = (e > 0.f) ? e : 0.2f * e;
            s1_alpha[w][lane] = __expf(e - m) * rden;
        }
        for (int e = team; e < cn; e += 4) {
            float a = s1_alpha[w][e];
            float4 hv = *(const float4*)&h[(size_t)s1_src[w][e] * 64 + c * 4];
            acc.x += a * hv.x; acc.y += a * hv.y;
            acc.z += a * hv.z; acc.w += a * hv.w;
        }
    }
    // fixed-order team combine: (t0+t1) + (t2+t3) per lane group
    acc.x += __shfl_xor(acc.x, 16, 64);
    acc.y += __shfl_xor(acc.y, 16, 64);
    acc.z += __shfl_xor(acc.z, 16, 64);
    acc.w += __shfl_xor(acc.w, 16, 64);
    acc.x += __shfl_xor(acc.x, 32, 64);
    acc.y += __shfl_xor(acc.y, 32, 64);
    acc.z += __shfl_xor(acc.z, 32, 64);
    acc.w += __shfl_xor(acc.w, 32, 64);
    if (team == 0) {
        float4 bv = *(const float4*)&bias[c * 4];
        *(float4*)&of[(size_t)dst * 64 + c * 4] =
            make_float4(acc.x + bv.x, acc.y + bv.y, acc.z + bv.z, acc.w + bv.w);
    }
}

// ---------------- classifier ----------------
__global__ void classifier_kernel(const float* __restrict__ x, const float* __restrict__ wc,
                                  const float* __restrict__ bc, float* __restrict__ out) {
    int n = blockIdx.x * blockDim.x + threadIdx.x;
    if (n >= N_NODES) return;
    float acc[NC] = {bc[0], bc[1], bc[2], bc[3]};
    for (int c = 0; c < 64; ++c) {
        float xv = x[(size_t)n * 64 + c];
        #pragma unroll
        for (int k = 0; k < NC; ++k) acc[k] += xv * wc[c * NC + k];
    }
    #pragma unroll
    for (int k = 0; k < NC; ++k) out[(size_t)n * NC + k] = acc[k];
}

extern "C" void kernel_launch(void* const* d_in, const int* in_sizes, int n_in,
                              void* d_out, int out_size, void* d_ws, size_t ws_size,
                              hipStream_t stream) {
    const float* x   = (const float*)d_in[0];
    const int*   ei  = (const int*)d_in[1];
    const float* w1  = (const float*)d_in[2];
    const float* as1 = (const float*)d_in[3];
    const float* ad1 = (const float*)d_in[4];
    const float* b1  = (const float*)d_in[5];
    const float* w2  = (const float*)d_in[6];
    const float* as2 = (const float*)d_in[7];
    const float* ad2 = (const float*)d_in[8];
    const float* b2  = (const float*)d_in[9];
    const float* w3  = (const float*)d_in[10];
    const float* as3 = (const float*)d_in[11];
    const float* ad3 = (const float*)d_in[12];
    const float* b3  = (const float*)d_in[13];
    const float* wc  = (const float*)d_in[14];
    const float* bc  = (const float*)d_in[15];
    float* out = (float*)d_out;

    char* ws = (char*)d_ws;
    size_t off = 0;
    auto alloc = [&](size_t bytes) -> char* {
        char* p = ws + off;
        off = (off + bytes + 255) & ~(size_t)255;
        return p;
    };

    int* counts  = (int*)alloc(N_NODES * 4);
    int* cursor  = (int*)alloc(N_NODES * 4);
    int* row_ptr = (int*)alloc((N_NODES + 1) * 4);
    int* colidx  = (int*)alloc(ET * 4);
    float* als   = (float*)alloc(N_NODES * 4 * 4);
    float* ald   = (float*)alloc(N_NODES * 4 * 4);
    float* B0    = (float*)alloc((size_t)N_NODES * HC * 4);

    ushort_t* xh   = (ushort_t*)alloc((size_t)N_NODES * F_IN * 2);
    ushort_t* xl   = (ushort_t*)alloc((size_t)N_NODES * F_IN * 2);
    ushort_t* w1Th = (ushort_t*)alloc((size_t)F_IN * HC * 2);
    ushort_t* w1Tl = (ushort_t*)alloc((size_t)F_IN * HC * 2);
    ushort_t* w2Th = (ushort_t*)alloc((size_t)HC * HC * 2);
    ushort_t* w2Tl = (ushort_t*)alloc((size_t)HC * HC * 2);
    ushort_t* w3Th = (ushort_t*)alloc((size_t)HC * 64 * 2);
    ushort_t* w3Tl = (ushort_t*)alloc((size_t)HC * 64 * 2);
    ushort_t* B1h  = (ushort_t*)alloc((size_t)N_NODES * HC * 2);
    ushort_t* B1l  = (ushort_t*)alloc((size_t)N_NODES * HC * 2);
    float*    B1f  = (float*)alloc((size_t)N_NODES * 64 * 4);

    // ---- CSR build ----
    hipMemsetAsync(counts, 0, N_NODES * sizeof(int), stream);
    int eb = (ET + 255) / 256;
    count_kernel<<<eb, 256, 0, stream>>>(ei, counts);
    scan_kernel<<<1, 1024, 0, stream>>>(counts, row_ptr, cursor);
    scatter_kernel<<<eb, 256, 0, stream>>>(ei, cursor, colidx);

    // ---- precision split ----
    split_rows<<<2048, 256, 0, stream>>>(x, xh, xl, (int)((size_t)N_NODES * F_IN / 4));
    split_T<<<(F_IN * HC + 255) / 256, 256, 0, stream>>>(w1, w1Th, w1Tl, F_IN, HC);
    split_T<<<(HC * HC + 255) / 256, 256, 0, stream>>>(w2, w2Th, w2Tl, HC, HC);
    split_T<<<(HC * 64 + 255) / 256, 256, 0, stream>>>(w3, w3Th, w3Tl, HC, 64);

    const int nwg12 = ((N_NODES + 127) / 128) * (HC / 64);   // 157*4 = 628
    // ---- layer 1 ----
    gemm_mfma<128, 64, 4><<<nwg12, 256, 0, stream>>>(xh, xl, w1Th, w1Tl, B0, N_NODES, F_IN, HC);
    al_kernel<4><<<N_NODES, 256, 0, stream>>>(B0, as1, ad1, als, ald);
    agg4_kernel<true><<<N_NODES, 256, 0, stream>>>(B0, als, ald, row_ptr, colidx, b1, B1h, B1l, nullptr);
    // ---- layer 2 ----
    gemm_mfma<128, 64, 4><<<nwg12, 256, 0, stream>>>(B1h, B1l, w2Th, w2Tl, B0, N_NODES, HC, HC);
    al_kernel<4><<<N_NODES, 256, 0, stream>>>(B0, as2, ad2, als, ald);
    agg4_kernel<true><<<N_NODES, 256, 0, stream>>>(B0, als, ald, row_ptr, colidx, b2, B1h, B1l, nullptr);
    // ---- layer 3 (H=1, C=64) ----
    const int nwg3 = (N_NODES + 63) / 64;                    // 313
    gemm_mfma<64, 64, 1><<<nwg3, 256, 0, stream>>>(B1h, B1l, w3Th, w3Tl, B0, N_NODES, HC, 64);
    al_kernel<1><<<N_NODES, 64, 0, stream>>>(B0, as3, ad3, als, ald);
    agg1_kernel<<<(N_NODES + 3) / 4, 256, 0, stream>>>(B0, als, ald, row_ptr, colidx, b3, B1f);
    // ---- classifier ----
    classifier_kernel<<<(N_NODES + 255) / 256, 256, 0, stream>>>(B1f, wc, bc, out);
}